// Round 2
// baseline (3526.040 us; speedup 1.0000x reference)
//
#include <hip/hip_runtime.h>
#include <hip/hip_bf16.h>

#define TREES_ 50
#define PER_ 2047
#define NN_ (TREES_ * PER_)   // 102350 nodes
#define HD 512

typedef __attribute__((ext_vector_type(8))) short s8v;   // 8 bf16 (4 VGPRs)
typedef __attribute__((ext_vector_type(4))) short s4v;   // 4 bf16
typedef __attribute__((ext_vector_type(4))) float f4v;   // MFMA C/D

__device__ __forceinline__ unsigned short f2bf(float f) {
  union { float f; unsigned u; } v; v.f = f;
  unsigned r = v.u + 0x7FFFu + ((v.u >> 16) & 1u);   // RNE
  return (unsigned short)(r >> 16);
}
__device__ __forceinline__ float bf2f(unsigned short s) {
  union { unsigned u; float f; } v; v.u = ((unsigned)s) << 16;
  return v.f;
}
__device__ __forceinline__ float sigm(float x) { return 1.f / (1.f + __expf(-x)); }
__device__ __forceinline__ float tanh_s(float x) {   // overflow-safe tanh
  float ax = fabsf(x);
  float e = __expf(2.f * ax);
  float t = 1.f - 2.f / (e + 1.f);
  return copysignf(t, x);
}
__device__ __forceinline__ f4v fz4() { f4v z; z[0]=0.f; z[1]=0.f; z[2]=0.f; z[3]=0.f; return z; }

// ---------------- weight prep: fp32 -> bf16 (+concat) -------------------
// Wcat [2048][512]  rows 0-1535 = W_iou_w, rows 1536-2047 = W_f_w
// Ucat [1536][1024] row j: k<512 -> U_iou_l[j][k], k>=512 -> U_iou_r[j][k-512]
// UflB/UfrB [512][512]
__global__ __launch_bounds__(256) void prep_weights(
    const float* __restrict__ Wiou, const float* __restrict__ Wf,
    const float* __restrict__ Ul,  const float* __restrict__ Ur,
    const float* __restrict__ Ufl, const float* __restrict__ Ufr,
    unsigned short* __restrict__ Wcat, unsigned short* __restrict__ Ucat,
    unsigned short* __restrict__ UflB, unsigned short* __restrict__ UfrB) {
  int i = blockIdx.x * 256 + threadIdx.x;
  if (i < 2048 * 512) {
    int r = i >> 9, c = i & 511;
    float v = (r < 1536) ? Wiou[r * 512 + c] : Wf[(r - 1536) * 512 + c];
    Wcat[i] = f2bf(v);
  }
  if (i < 1536 * 1024) {
    int r = i >> 10, c = i & 1023;
    float v = (c < 512) ? Ul[r * 512 + c] : Ur[r * 512 + (c - 512)];
    Ucat[i] = f2bf(v);
  }
  if (i < 512 * 512) { UflB[i] = f2bf(Ufl[i]); UfrB[i] = f2bf(Ufr[i]); }
}

// ---------------- PRE GEMM: PRE[N,2048] = feat @ [W_iou;W_f]^T + bias ----
// BM=64, block covers all 2048 cols; 4 waves x 32 col-tiles each.
__global__ __launch_bounds__(256) void pre_gemm(
    const float* __restrict__ feat, const unsigned short* __restrict__ Wcat,
    const float* __restrict__ biou, const float* __restrict__ bfb,
    unsigned short* __restrict__ PRE) {
  __shared__ __align__(16) unsigned short As[64 * 512];   // 64 KB, swizzled
  const int tid = threadIdx.x;
  const int bm = blockIdx.x;
#pragma unroll
  for (int jj = 0; jj < 32; ++jj) {
    int ch = jj * 256 + tid;          // 8192 chunks of 4 floats
    int row = ch >> 7;
    int c4 = ch & 127;
    int g = bm * 64 + row;
    float4 f = make_float4(0.f, 0.f, 0.f, 0.f);
    if (g < NN_) f = *(const float4*)(feat + g * 512 + c4 * 4);
    s4v v;
    v[0] = (short)f2bf(f.x); v[1] = (short)f2bf(f.y);
    v[2] = (short)f2bf(f.z); v[3] = (short)f2bf(f.w);
    int byte = row * 1024 + c4 * 8;
    byte ^= ((row >> 1) & 7) << 4;    // bank-conflict swizzle
    *(s4v*)((char*)As + byte) = v;
  }
  __syncthreads();
  const int wid = tid >> 6, lane = tid & 63;
  const int lr = lane & 15, lg = lane >> 4;
  // 2048 cols / 16 = 128 col-tiles total -> 32 per wave (BUG FIX: was 8)
  for (int ct = 0; ct < 32; ++ct) {
    const int cb = (wid * 32 + ct) * 16;
    const int colg = cb + lr;
    f4v acc[4] = {fz4(), fz4(), fz4(), fz4()};
    const unsigned short* bp = Wcat + colg * 512 + lg * 8;
#pragma unroll 4
    for (int k0 = 0; k0 < 16; ++k0) {
      s8v b = *(const s8v*)(bp + k0 * 32);
#pragma unroll
      for (int mt = 0; mt < 4; ++mt) {
        int arow = mt * 16 + lr;
        int byte = arow * 1024 + (k0 * 32 + lg * 8) * 2;
        byte ^= ((arow >> 1) & 7) << 4;
        s8v a = *(const s8v*)((char*)As + byte);
        acc[mt] = __builtin_amdgcn_mfma_f32_16x16x32_bf16(a, b, acc[mt], 0, 0, 0);
      }
    }
    float bias = (colg < 1536) ? biou[colg] : bfb[colg - 1536];
#pragma unroll
    for (int mt = 0; mt < 4; ++mt) {
#pragma unroll
      for (int r = 0; r < 4; ++r) {
        int g = bm * 64 + mt * 16 + lg * 4 + r;   // C/D: row=(l>>4)*4+r, col=l&15
        if (g < NN_) PRE[g * 2048 + colg] = f2bf(acc[mt][r] + bias);
      }
    }
  }
}

// ---------------- leaves: pure elementwise from PRE ----------------------
__global__ __launch_bounds__(256) void leaf_kernel(
    const unsigned short* __restrict__ PRE,
    float* __restrict__ h_out, float* __restrict__ c_out,
    unsigned short* __restrict__ HB) {
  int idx = blockIdx.x * 256 + threadIdx.x;   // 51200 rows * 128 chunks
  int r = idx >> 7;
  int c4 = (idx & 127) << 2;
  int t = r >> 10, li = r & 1023;
  int g = t * PER_ + li;
  const unsigned short* pr = PRE + (size_t)g * 2048;
  ushort4 iv = *(const ushort4*)(pr + c4);
  ushort4 ov = *(const ushort4*)(pr + 512 + c4);
  ushort4 uv = *(const ushort4*)(pr + 1024 + c4);
  float4 hv, cv; ushort4 hb;
  float cc, hh;
  cc = sigm(bf2f(iv.x)) * tanh_s(bf2f(uv.x)); hh = sigm(bf2f(ov.x)) * tanh_s(cc);
  cv.x = cc; hv.x = hh; hb.x = f2bf(hh);
  cc = sigm(bf2f(iv.y)) * tanh_s(bf2f(uv.y)); hh = sigm(bf2f(ov.y)) * tanh_s(cc);
  cv.y = cc; hv.y = hh; hb.y = f2bf(hh);
  cc = sigm(bf2f(iv.z)) * tanh_s(bf2f(uv.z)); hh = sigm(bf2f(ov.z)) * tanh_s(cc);
  cv.z = cc; hv.z = hh; hb.z = f2bf(hh);
  cc = sigm(bf2f(iv.w)) * tanh_s(bf2f(uv.w)); hh = sigm(bf2f(ov.w)) * tanh_s(cc);
  cv.w = cc; hv.w = hh; hb.w = f2bf(hh);
  *(float4*)(h_out + (size_t)g * 512 + c4) = hv;
  *(float4*)(c_out + (size_t)g * 512 + c4) = cv;
  *(ushort4*)(HB + (size_t)g * 512 + c4) = hb;
}

// ---------------- fused level kernel: 16 parents / block -----------------
__global__ __launch_bounds__(256) void level_kernel(
    const unsigned short* __restrict__ PRE,
    const unsigned short* __restrict__ Ucat,
    const unsigned short* __restrict__ UflB,
    const unsigned short* __restrict__ UfrB,
    float* __restrict__ h_out, float* __restrict__ c_out,
    unsigned short* __restrict__ HB,
    int P, int shift, int start_l, int start_lm1) {
  __shared__ __align__(16) unsigned short chh[32 * 512];  // children h, 32 KB
  __shared__ float fcsum[16 * 512];                       // per-parent fc sum, 32 KB
  const int tid = threadIdx.x;
  const int pb = blockIdx.x;
  const int nmask = (1 << shift) - 1;
  // stage 32 children-h rows (bf16), swizzled
#pragma unroll
  for (int jj = 0; jj < 8; ++jj) {
    int ch = jj * 256 + tid;           // 2048 chunks of 16B
    int row = ch >> 6;
    int c16 = ch & 63;
    int pl = row >> 1;
    int p = pb * 16 + pl;
    s8v v = {0, 0, 0, 0, 0, 0, 0, 0};
    if (p < P) {
      int t = p >> shift, k = p & nmask;
      int cg = t * PER_ + start_lm1 + 2 * k + (row & 1);
      v = *(const s8v*)(HB + (size_t)cg * 512 + c16 * 8);
    }
    int byte = row * 1024 + c16 * 16;
    byte ^= ((row >> 1) & 7) << 4;
    *(s8v*)((char*)chh + byte) = v;
  }
  __syncthreads();
  const int wid = tid >> 6, lane = tid & 63;
  const int lr = lane & 15, lg = lane >> 4;
  // ---- Phase A: f-gate GEMM [32 children,512] @ Ufl/Ufr^T, fc into fcsum
  for (int ct = 0; ct < 8; ++ct) {
    const int cb = (wid * 8 + ct) * 16;
    const int col = cb + lr;
    f4v al[2] = {fz4(), fz4()}, ar_[2] = {fz4(), fz4()};
    const unsigned short* bl = UflB + col * 512 + lg * 8;
    const unsigned short* br = UfrB + col * 512 + lg * 8;
#pragma unroll 4
    for (int k0 = 0; k0 < 16; ++k0) {
      s8v vbl = *(const s8v*)(bl + k0 * 32);
      s8v vbr = *(const s8v*)(br + k0 * 32);
#pragma unroll
      for (int mt = 0; mt < 2; ++mt) {
        int arow = mt * 16 + lr;
        int byte = arow * 1024 + (k0 * 32 + lg * 8) * 2;
        byte ^= ((arow >> 1) & 7) << 4;
        s8v a = *(const s8v*)((char*)chh + byte);
        al[mt]  = __builtin_amdgcn_mfma_f32_16x16x32_bf16(a, vbl, al[mt], 0, 0, 0);
        ar_[mt] = __builtin_amdgcn_mfma_f32_16x16x32_bf16(a, vbr, ar_[mt], 0, 0, 0);
      }
    }
#pragma unroll
    for (int mt = 0; mt < 2; ++mt) {
      float fc[4];
#pragma unroll
      for (int r = 0; r < 4; ++r) {
        int j = mt * 16 + lg * 4 + r;        // child row in block
        int pl = j >> 1;
        int p = pb * 16 + pl;
        float fcv = 0.f;
        if (p < P) {
          int t = p >> shift, k = p & nmask;
          int pg = t * PER_ + start_l + k;
          int cg = t * PER_ + start_lm1 + 2 * k + (j & 1);
          float wf = bf2f(PRE[(size_t)pg * 2048 + 1536 + col]);
          float cc = c_out[(size_t)cg * 512 + col];
          fcv = (sigm(wf + al[mt][r]) + sigm(wf + ar_[mt][r])) * cc;
        }
        fc[r] = fcv;
      }
      // rows 2k,2k+1 sit in reg pairs of the SAME lane -> no atomics
      int plo = mt * 8 + lg * 2;
      fcsum[plo * 512 + col]       = fc[0] + fc[1];
      fcsum[(plo + 1) * 512 + col] = fc[2] + fc[3];
    }
  }
  __syncthreads();
  // ---- Phase B: iou GEMM [16 parents,1024(h_l|h_r)] @ Ucat^T + epilogue
  for (int ct = 0; ct < 8; ++ct) {
    const int cb = (wid * 8 + ct) * 16;
    const int col = cb + lr;
    f4v ai = fz4(), ao = fz4(), au = fz4();
    const unsigned short* bi = Ucat + (size_t)col * 1024 + lg * 8;
    const unsigned short* bo = Ucat + (size_t)(512 + col) * 1024 + lg * 8;
    const unsigned short* bu = Ucat + (size_t)(1024 + col) * 1024 + lg * 8;
#pragma unroll 2
    for (int k0 = 0; k0 < 32; ++k0) {
      int kk = k0 * 32 + lg * 8;
      int a2row = (lr << 1) | (kk >> 9);   // [16,1024] view onto [32,512] buffer
      int a2col = kk & 511;
      int byte = a2row * 1024 + a2col * 2;
      byte ^= ((a2row >> 1) & 7) << 4;
      s8v a = *(const s8v*)((char*)chh + byte);
      s8v vi = *(const s8v*)(bi + k0 * 32);
      s8v vo = *(const s8v*)(bo + k0 * 32);
      s8v vu = *(const s8v*)(bu + k0 * 32);
      ai = __builtin_amdgcn_mfma_f32_16x16x32_bf16(a, vi, ai, 0, 0, 0);
      ao = __builtin_amdgcn_mfma_f32_16x16x32_bf16(a, vo, ao, 0, 0, 0);
      au = __builtin_amdgcn_mfma_f32_16x16x32_bf16(a, vu, au, 0, 0, 0);
    }
#pragma unroll
    for (int r = 0; r < 4; ++r) {
      int pl = lg * 4 + r;
      int p = pb * 16 + pl;
      if (p < P) {
        int t = p >> shift, k = p & nmask;
        int pg = t * PER_ + start_l + k;
        float iv = ai[r] + bf2f(PRE[(size_t)pg * 2048 + col]);
        float ov = ao[r] + bf2f(PRE[(size_t)pg * 2048 + 512 + col]);
        float uv = au[r] + bf2f(PRE[(size_t)pg * 2048 + 1024 + col]);
        float cvv = sigm(iv) * tanh_s(uv) + fcsum[pl * 512 + col];
        float hvv = sigm(ov) * tanh_s(cvv);
        h_out[(size_t)pg * 512 + col] = hvv;
        c_out[(size_t)pg * 512 + col] = cvv;
        HB[(size_t)pg * 512 + col] = f2bf(hvv);
      }
    }
  }
}

__global__ void fill_sentinel(float* out, int n) {
  int i = blockIdx.x * 256 + threadIdx.x;
  if (i < n) out[i] = 12345.0f;   // distinguishable "workspace too small" marker
}

// ---------------- host launch -------------------------------------------
extern "C" void kernel_launch(void* const* d_in, const int* in_sizes, int n_in,
                              void* d_out, int out_size, void* d_ws, size_t ws_size,
                              hipStream_t stream) {
  (void)in_sizes; (void)n_in; (void)out_size;
  const float* feat = (const float*)d_in[0];
  const float* Wiou = (const float*)d_in[4];
  const float* biou = (const float*)d_in[5];
  const float* Ul   = (const float*)d_in[6];
  const float* Ur   = (const float*)d_in[7];
  const float* Wf   = (const float*)d_in[8];
  const float* bfb  = (const float*)d_in[9];
  const float* Ufl  = (const float*)d_in[10];
  const float* Ufr  = (const float*)d_in[11];
  float* h_out = (float*)d_out;
  float* c_out = h_out + (size_t)NN_ * 512;

  // workspace layout (bytes)
  const size_t OFF_PRE  = 0;
  const size_t SZ_PRE   = (size_t)NN_ * 2048 * 2;        // 419,225,600
  const size_t OFF_HB   = OFF_PRE + SZ_PRE;
  const size_t SZ_HB    = (size_t)NN_ * 512 * 2;         // 104,806,400
  const size_t OFF_WCAT = OFF_HB + SZ_HB;
  const size_t SZ_WCAT  = 2048 * 512 * 2;
  const size_t OFF_UCAT = OFF_WCAT + SZ_WCAT;
  const size_t SZ_UCAT  = 1536 * 1024 * 2;
  const size_t OFF_UFL  = OFF_UCAT + SZ_UCAT;
  const size_t SZ_UF    = 512 * 512 * 2;
  const size_t OFF_UFR  = OFF_UFL + SZ_UF;
  const size_t NEEDED   = OFF_UFR + SZ_UF;

  if (ws_size < NEEDED) {
    int n = 2 * NN_ * 512;
    fill_sentinel<<<(n + 255) / 256, 256, 0, stream>>>((float*)d_out, n);
    return;
  }

  char* ws = (char*)d_ws;
  unsigned short* PRE  = (unsigned short*)(ws + OFF_PRE);
  unsigned short* HB   = (unsigned short*)(ws + OFF_HB);
  unsigned short* WCAT = (unsigned short*)(ws + OFF_WCAT);
  unsigned short* UCAT = (unsigned short*)(ws + OFF_UCAT);
  unsigned short* UFLB = (unsigned short*)(ws + OFF_UFL);
  unsigned short* UFRB = (unsigned short*)(ws + OFF_UFR);

  prep_weights<<<6144, 256, 0, stream>>>(Wiou, Wf, Ul, Ur, Ufl, Ufr,
                                         WCAT, UCAT, UFLB, UFRB);
  pre_gemm<<<(NN_ + 63) / 64, 256, 0, stream>>>(feat, WCAT, biou, bfb, PRE);
  leaf_kernel<<<(TREES_ * 1024 * 128) / 256, 256, 0, stream>>>(PRE, h_out, c_out, HB);
  for (int l = 1; l <= 10; ++l) {
    int shift = 10 - l;
    int P = TREES_ << shift;
    int start_l   = 2048 - (1 << (11 - l));
    int start_lm1 = 2048 - (1 << (12 - l));
    int gb = (P + 15) / 16;
    level_kernel<<<gb, 256, 0, stream>>>(PRE, UCAT, UFLB, UFRB,
                                         h_out, c_out, HB,
                                         P, shift, start_l, start_lm1);
  }
}

// Round 3
// 2599.025 us; speedup vs baseline: 1.3567x; 1.3567x over previous
//
#include <hip/hip_runtime.h>
#include <hip/hip_bf16.h>

#define TREES_ 50
#define PER_ 2047
#define NN_ (TREES_ * PER_)   // 102350 nodes

typedef __attribute__((ext_vector_type(8))) short s8v;   // 8 bf16
typedef __attribute__((ext_vector_type(4))) short s4v;   // 4 bf16
typedef __attribute__((ext_vector_type(4))) float f4v;   // MFMA C/D

__device__ __forceinline__ unsigned short f2bf(float f) {
  union { float f; unsigned u; } v; v.f = f;
  unsigned r = v.u + 0x7FFFu + ((v.u >> 16) & 1u);   // RNE
  return (unsigned short)(r >> 16);
}
__device__ __forceinline__ float bf2f(unsigned short s) {
  union { unsigned u; float f; } v; v.u = ((unsigned)s) << 16;
  return v.f;
}
__device__ __forceinline__ float sigm(float x) { return 1.f / (1.f + __expf(-x)); }
__device__ __forceinline__ float tanh_s(float x) {
  float ax = fabsf(x);
  float e = __expf(2.f * ax);
  float t = 1.f - 2.f / (e + 1.f);
  return copysignf(t, x);
}
__device__ __forceinline__ f4v fz4() { f4v z; z[0]=0.f; z[1]=0.f; z[2]=0.f; z[3]=0.f; return z; }

// ---------------- weight prep: fp32 -> bf16 (+concat/interleave) ---------
// Wcat [2048][512] rows 0-1535=W_iou_w, 1536-2047=W_f_w
// Ucat [1536][1024] row j: k<512 -> U_iou_l, k>=512 -> U_iou_r
// Uflr [1024][512] row 2c=Ufl[c], row 2c+1=Ufr[c]   (interleaved for G1)
__global__ __launch_bounds__(256) void prep_weights(
    const float* __restrict__ Wiou, const float* __restrict__ Wf,
    const float* __restrict__ Ul,  const float* __restrict__ Ur,
    const float* __restrict__ Ufl, const float* __restrict__ Ufr,
    unsigned short* __restrict__ Wcat, unsigned short* __restrict__ Ucat,
    unsigned short* __restrict__ UflB, unsigned short* __restrict__ UfrB,
    unsigned short* __restrict__ Uflr) {
  int i = blockIdx.x * 256 + threadIdx.x;
  if (i < 2048 * 512) {
    int r = i >> 9, c = i & 511;
    float v = (r < 1536) ? Wiou[r * 512 + c] : Wf[(r - 1536) * 512 + c];
    Wcat[i] = f2bf(v);
  }
  if (i < 1536 * 1024) {
    int r = i >> 10, c = i & 1023;
    float v = (c < 512) ? Ul[r * 512 + c] : Ur[r * 512 + (c - 512)];
    Ucat[i] = f2bf(v);
  }
  if (i < 512 * 512) { UflB[i] = f2bf(Ufl[i]); UfrB[i] = f2bf(Ufr[i]); }
  if (i < 1024 * 512) {
    int r = i >> 9, k = i & 511;
    int c = r >> 1, s = r & 1;
    Uflr[i] = f2bf(s ? Ufr[c * 512 + k] : Ufl[c * 512 + k]);
  }
}

// ============ tiled 128x128 GEMM cores (reg-staged, swizzled LDS) ========
// LDS layout: X[128][64] bf16, byte = row*128 + ((c16 ^ (row&7))<<4), c16=chunk of 8 elems
#define STAGE_CHUNK(q, ROWV, C16V) int ROWV = (q) >> 3; int C16V = (q) & 7;
#define LDS_BYTE(row, c16) ((row) * 128 + (((c16) ^ ((row) & 7)) << 4))

// ---- pre GEMM: PRE[N,2048] = feat(f32) @ Wcat^T + bias ------------------
__global__ __launch_bounds__(256) void pre_gemm(
    const float* __restrict__ feat, const unsigned short* __restrict__ Wcat,
    const float* __restrict__ biou, const float* __restrict__ bfb,
    unsigned short* __restrict__ PRE) {
  __shared__ __align__(16) unsigned short As[128 * 64];
  __shared__ __align__(16) unsigned short Bs[128 * 64];
  const int tid = threadIdx.x;
  const int bid = blockIdx.x;
  const int tn = bid & 15, tm = bid >> 4;
  const int wid = tid >> 6, lane = tid & 63;
  const int wr = wid >> 1, wc = wid & 1;
  const int lr = lane & 15, lg = lane >> 4;
  f4v acc[4][4];
#pragma unroll
  for (int i = 0; i < 4; ++i)
#pragma unroll
    for (int j = 0; j < 4; ++j) acc[i][j] = fz4();
  for (int k0 = 0; k0 < 512; k0 += 64) {
#pragma unroll
    for (int L = 0; L < 4; ++L) {
      STAGE_CHUNK(L * 256 + tid, row, c16)
      {  // A (f32 -> bf16)
        int g = tm * 128 + row; if (g >= NN_) g = NN_ - 1;
        const float* src = feat + (size_t)g * 512 + k0 + c16 * 8;
        float4 f0 = *(const float4*)src;
        float4 f1 = *(const float4*)(src + 4);
        s8v v;
        v[0] = (short)f2bf(f0.x); v[1] = (short)f2bf(f0.y);
        v[2] = (short)f2bf(f0.z); v[3] = (short)f2bf(f0.w);
        v[4] = (short)f2bf(f1.x); v[5] = (short)f2bf(f1.y);
        v[6] = (short)f2bf(f1.z); v[7] = (short)f2bf(f1.w);
        *(s8v*)((char*)As + LDS_BYTE(row, c16)) = v;
      }
      {  // B
        int n = tn * 128 + row;
        s8v v = *(const s8v*)(Wcat + (size_t)n * 512 + k0 + c16 * 8);
        *(s8v*)((char*)Bs + LDS_BYTE(row, c16)) = v;
      }
    }
    __syncthreads();
#pragma unroll
    for (int kk = 0; kk < 2; ++kk) {
      s8v af[4], bf_[4];
#pragma unroll
      for (int i = 0; i < 4; ++i) {
        int R = wr * 64 + i * 16 + lr;
        af[i] = *(const s8v*)((char*)As + LDS_BYTE(R, kk * 4 + lg));
      }
#pragma unroll
      for (int j = 0; j < 4; ++j) {
        int R = wc * 64 + j * 16 + lr;
        bf_[j] = *(const s8v*)((char*)Bs + LDS_BYTE(R, kk * 4 + lg));
      }
#pragma unroll
      for (int i = 0; i < 4; ++i)
#pragma unroll
        for (int j = 0; j < 4; ++j)
          acc[i][j] = __builtin_amdgcn_mfma_f32_16x16x32_bf16(af[i], bf_[j], acc[i][j], 0, 0, 0);
    }
    __syncthreads();
  }
#pragma unroll
  for (int i = 0; i < 4; ++i)
#pragma unroll
    for (int j = 0; j < 4; ++j) {
      int n = tn * 128 + wc * 64 + j * 16 + lr;
      float bias = (n < 1536) ? biou[n] : bfb[n - 1536];
#pragma unroll
      for (int r = 0; r < 4; ++r) {
        int m = tm * 128 + wr * 64 + i * 16 + lg * 4 + r;
        if (m < NN_) PRE[(size_t)m * 2048 + n] = f2bf(acc[i][j][r] + bias);
      }
    }
}

// ---- G1: f-gate GEMM [2P,512] @ Uflr^T, fused fc; fcsum -> h_out --------
__global__ __launch_bounds__(256) void g1_kernel(
    const unsigned short* __restrict__ HB, const unsigned short* __restrict__ Uflr,
    const unsigned short* __restrict__ PRE, const float* __restrict__ c_out,
    float* __restrict__ h_out,
    int shift, int start_l, int start_lm1) {
  __shared__ __align__(16) unsigned short As[128 * 64];
  __shared__ __align__(16) unsigned short Bs[128 * 64];
  const int tid = threadIdx.x;
  const int bid = blockIdx.x;
  const int tn = bid & 7, tm = bid >> 3;
  const int cmask = (2 << shift) - 1;   // child-index mask (shift+1 bits)
  const int wid = tid >> 6, lane = tid & 63;
  const int wr = wid >> 1, wc = wid & 1;
  const int lr = lane & 15, lg = lane >> 4;
  f4v acc[4][4];
#pragma unroll
  for (int i = 0; i < 4; ++i)
#pragma unroll
    for (int j = 0; j < 4; ++j) acc[i][j] = fz4();
  for (int k0 = 0; k0 < 512; k0 += 64) {
#pragma unroll
    for (int L = 0; L < 4; ++L) {
      STAGE_CHUNK(L * 256 + tid, row, c16)
      {  // A: child h rows (M2 = 2P is always a multiple of 128 for l<=5)
        int jg = tm * 128 + row;
        int t = jg >> (shift + 1), idx = jg & cmask;
        const unsigned short* src =
            HB + (size_t)(t * PER_ + start_lm1 + idx) * 512 + k0 + c16 * 8;
        *(s8v*)((char*)As + LDS_BYTE(row, c16)) = *(const s8v*)src;
      }
      {  // B
        int n = tn * 128 + row;
        s8v v = *(const s8v*)(Uflr + (size_t)n * 512 + k0 + c16 * 8);
        *(s8v*)((char*)Bs + LDS_BYTE(row, c16)) = v;
      }
    }
    __syncthreads();
#pragma unroll
    for (int kk = 0; kk < 2; ++kk) {
      s8v af[4], bf_[4];
#pragma unroll
      for (int i = 0; i < 4; ++i) {
        int R = wr * 64 + i * 16 + lr;
        af[i] = *(const s8v*)((char*)As + LDS_BYTE(R, kk * 4 + lg));
      }
#pragma unroll
      for (int j = 0; j < 4; ++j) {
        int R = wc * 64 + j * 16 + lr;
        bf_[j] = *(const s8v*)((char*)Bs + LDS_BYTE(R, kk * 4 + lg));
      }
#pragma unroll
      for (int i = 0; i < 4; ++i)
#pragma unroll
        for (int j = 0; j < 4; ++j)
          acc[i][j] = __builtin_amdgcn_mfma_f32_16x16x32_bf16(af[i], bf_[j], acc[i][j], 0, 0, 0);
    }
    __syncthreads();
  }
  // epilogue: col n = 2*hcol + (0:Ufl | 1:Ufr); pair via shfl_xor(1);
  // child pair (rows r=0,1 and r=2,3 within lane) reduces in-register.
  const int pmask = (1 << shift) - 1;
#pragma unroll
  for (int i = 0; i < 4; ++i) {
    int mbase = tm * 128 + wr * 64 + i * 16;   // even
#pragma unroll
    for (int j = 0; j < 4; ++j) {
      int nn = tn * 128 + wc * 64 + j * 16 + lr;
      int hcol = nn >> 1;
      float fc[4];
#pragma unroll
      for (int r = 0; r < 4; ++r) {
        int m = mbase + lg * 4 + r;            // child index
        int pidx = m >> 1;
        int t = pidx >> shift, k = pidx & pmask;
        float wf = bf2f(PRE[(size_t)(t * PER_ + start_l + k) * 2048 + 1536 + hcol]);
        float sv = sigm(wf + acc[i][j][r]);
        float spair = sv + __shfl_xor(sv, 1, 64);
        float cc = 0.f;
        if ((lr & 1) == 0)
          cc = c_out[(size_t)(t * PER_ + start_lm1 + (m & cmask)) * 512 + hcol];
        fc[r] = spair * cc;
      }
      if ((lr & 1) == 0) {
        int p0 = (mbase >> 1) + lg * 2;
        int t0 = p0 >> shift, k0p = p0 & pmask;
        h_out[(size_t)(t0 * PER_ + start_l + k0p) * 512 + hcol] = fc[0] + fc[1];
        int p1 = p0 + 1;
        int t1 = p1 >> shift, k1p = p1 & pmask;
        h_out[(size_t)(t1 * PER_ + start_l + k1p) * 512 + hcol] = fc[2] + fc[3];
      }
    }
  }
}

// ---- G2: iou GEMM [P,1024] @ Ucat^T + PRE -> IOU (bf16) -----------------
__global__ __launch_bounds__(256) void g2_kernel(
    const unsigned short* __restrict__ HB, const unsigned short* __restrict__ Ucat,
    const unsigned short* __restrict__ PRE, unsigned short* __restrict__ IOU,
    int P, int shift, int start_l, int start_lm1) {
  __shared__ __align__(16) unsigned short As[128 * 64];
  __shared__ __align__(16) unsigned short Bs[128 * 64];
  const int tid = threadIdx.x;
  const int bid = blockIdx.x;
  const int tn = bid % 12, tm = bid / 12;
  const int pmask = (1 << shift) - 1;
  const int wid = tid >> 6, lane = tid & 63;
  const int wr = wid >> 1, wc = wid & 1;
  const int lr = lane & 15, lg = lane >> 4;
  f4v acc[4][4];
#pragma unroll
  for (int i = 0; i < 4; ++i)
#pragma unroll
    for (int j = 0; j < 4; ++j) acc[i][j] = fz4();
  for (int k0 = 0; k0 < 1024; k0 += 64) {
#pragma unroll
    for (int L = 0; L < 4; ++L) {
      STAGE_CHUNK(L * 256 + tid, row, c16)
      {  // A: hcat row p = children (2k,2k+1) h concatenated (contiguous in HB)
        int p = tm * 128 + row; if (p >= P) p = 0;
        int t = p >> shift, k = p & pmask;
        const unsigned short* src = HB + (size_t)(t * PER_ + start_lm1) * 512 +
                                    (size_t)k * 1024 + k0 + c16 * 8;
        *(s8v*)((char*)As + LDS_BYTE(row, c16)) = *(const s8v*)src;
      }
      {  // B
        int n = tn * 128 + row;
        s8v v = *(const s8v*)(Ucat + (size_t)n * 1024 + k0 + c16 * 8);
        *(s8v*)((char*)Bs + LDS_BYTE(row, c16)) = v;
      }
    }
    __syncthreads();
#pragma unroll
    for (int kk = 0; kk < 2; ++kk) {
      s8v af[4], bf_[4];
#pragma unroll
      for (int i = 0; i < 4; ++i) {
        int R = wr * 64 + i * 16 + lr;
        af[i] = *(const s8v*)((char*)As + LDS_BYTE(R, kk * 4 + lg));
      }
#pragma unroll
      for (int j = 0; j < 4; ++j) {
        int R = wc * 64 + j * 16 + lr;
        bf_[j] = *(const s8v*)((char*)Bs + LDS_BYTE(R, kk * 4 + lg));
      }
#pragma unroll
      for (int i = 0; i < 4; ++i)
#pragma unroll
        for (int j = 0; j < 4; ++j)
          acc[i][j] = __builtin_amdgcn_mfma_f32_16x16x32_bf16(af[i], bf_[j], acc[i][j], 0, 0, 0);
    }
    __syncthreads();
  }
#pragma unroll
  for (int i = 0; i < 4; ++i)
#pragma unroll
    for (int j = 0; j < 4; ++j) {
      int n = tn * 128 + wc * 64 + j * 16 + lr;
#pragma unroll
      for (int r = 0; r < 4; ++r) {
        int m = tm * 128 + wr * 64 + i * 16 + lg * 4 + r;
        if (m < P) {
          int t = m >> shift, k = m & pmask;
          size_t pg = (size_t)(t * PER_ + start_l + k);
          IOU[(size_t)m * 1536 + n] = f2bf(acc[i][j][r] + bf2f(PRE[pg * 2048 + n]));
        }
      }
    }
}

// ---- G3: elementwise combine; reads fcsum from h_out, overwrites with h -
__global__ __launch_bounds__(256) void g3_kernel(
    const unsigned short* __restrict__ IOU,
    float* __restrict__ h_out, float* __restrict__ c_out,
    unsigned short* __restrict__ HB, int P, int shift, int start_l) {
  int idx = blockIdx.x * 256 + threadIdx.x;   // P*128 threads
  int p = idx >> 7;
  if (p >= P) return;
  int c4 = (idx & 127) << 2;
  int t = p >> shift, k = p & ((1 << shift) - 1);
  size_t pg = (size_t)(t * PER_ + start_l + k);
  const unsigned short* ir = IOU + (size_t)p * 1536;
  ushort4 iv = *(const ushort4*)(ir + c4);
  ushort4 ov = *(const ushort4*)(ir + 512 + c4);
  ushort4 uv = *(const ushort4*)(ir + 1024 + c4);
  float4 fcs = *(const float4*)(h_out + pg * 512 + c4);
  float4 hv, cv; ushort4 hb;
  float cc, hh;
  cc = sigm(bf2f(iv.x)) * tanh_s(bf2f(uv.x)) + fcs.x; hh = sigm(bf2f(ov.x)) * tanh_s(cc);
  cv.x = cc; hv.x = hh; hb.x = f2bf(hh);
  cc = sigm(bf2f(iv.y)) * tanh_s(bf2f(uv.y)) + fcs.y; hh = sigm(bf2f(ov.y)) * tanh_s(cc);
  cv.y = cc; hv.y = hh; hb.y = f2bf(hh);
  cc = sigm(bf2f(iv.z)) * tanh_s(bf2f(uv.z)) + fcs.z; hh = sigm(bf2f(ov.z)) * tanh_s(cc);
  cv.z = cc; hv.z = hh; hb.z = f2bf(hh);
  cc = sigm(bf2f(iv.w)) * tanh_s(bf2f(uv.w)) + fcs.w; hh = sigm(bf2f(ov.w)) * tanh_s(cc);
  cv.w = cc; hv.w = hh; hb.w = f2bf(hh);
  *(float4*)(h_out + pg * 512 + c4) = hv;
  *(float4*)(c_out + pg * 512 + c4) = cv;
  *(ushort4*)(HB + pg * 512 + c4) = hb;
}

// ---------------- leaves: pure elementwise from PRE ----------------------
__global__ __launch_bounds__(256) void leaf_kernel(
    const unsigned short* __restrict__ PRE,
    float* __restrict__ h_out, float* __restrict__ c_out,
    unsigned short* __restrict__ HB) {
  int idx = blockIdx.x * 256 + threadIdx.x;
  int r = idx >> 7;
  int c4 = (idx & 127) << 2;
  int t = r >> 10, li = r & 1023;
  int g = t * PER_ + li;
  const unsigned short* pr = PRE + (size_t)g * 2048;
  ushort4 iv = *(const ushort4*)(pr + c4);
  ushort4 ov = *(const ushort4*)(pr + 512 + c4);
  ushort4 uv = *(const ushort4*)(pr + 1024 + c4);
  float4 hv, cv; ushort4 hb;
  float cc, hh;
  cc = sigm(bf2f(iv.x)) * tanh_s(bf2f(uv.x)); hh = sigm(bf2f(ov.x)) * tanh_s(cc);
  cv.x = cc; hv.x = hh; hb.x = f2bf(hh);
  cc = sigm(bf2f(iv.y)) * tanh_s(bf2f(uv.y)); hh = sigm(bf2f(ov.y)) * tanh_s(cc);
  cv.y = cc; hv.y = hh; hb.y = f2bf(hh);
  cc = sigm(bf2f(iv.z)) * tanh_s(bf2f(uv.z)); hh = sigm(bf2f(ov.z)) * tanh_s(cc);
  cv.z = cc; hv.z = hh; hb.z = f2bf(hh);
  cc = sigm(bf2f(iv.w)) * tanh_s(bf2f(uv.w)); hh = sigm(bf2f(ov.w)) * tanh_s(cc);
  cv.w = cc; hv.w = hh; hb.w = f2bf(hh);
  *(float4*)(h_out + (size_t)g * 512 + c4) = hv;
  *(float4*)(c_out + (size_t)g * 512 + c4) = cv;
  *(ushort4*)(HB + (size_t)g * 512 + c4) = hb;
}

// ------- fused small-level kernel (levels 6-10), 16 parents / block ------
__global__ __launch_bounds__(256) void level_kernel(
    const unsigned short* __restrict__ PRE,
    const unsigned short* __restrict__ Ucat,
    const unsigned short* __restrict__ UflB,
    const unsigned short* __restrict__ UfrB,
    float* __restrict__ h_out, float* __restrict__ c_out,
    unsigned short* __restrict__ HB,
    int P, int shift, int start_l, int start_lm1) {
  __shared__ __align__(16) unsigned short chh[32 * 512];
  __shared__ float fcsum[16 * 512];
  const int tid = threadIdx.x;
  const int pb = blockIdx.x;
  const int nmask = (1 << shift) - 1;
#pragma unroll
  for (int jj = 0; jj < 8; ++jj) {
    int ch = jj * 256 + tid;
    int row = ch >> 6;
    int c16 = ch & 63;
    int pl = row >> 1;
    int p = pb * 16 + pl;
    s8v v = {0, 0, 0, 0, 0, 0, 0, 0};
    if (p < P) {
      int t = p >> shift, k = p & nmask;
      int cg = t * PER_ + start_lm1 + 2 * k + (row & 1);
      v = *(const s8v*)(HB + (size_t)cg * 512 + c16 * 8);
    }
    int byte = row * 1024 + c16 * 16;
    byte ^= ((row >> 1) & 7) << 4;
    *(s8v*)((char*)chh + byte) = v;
  }
  __syncthreads();
  const int wid = tid >> 6, lane = tid & 63;
  const int lr = lane & 15, lg = lane >> 4;
  for (int ct = 0; ct < 8; ++ct) {
    const int cb = (wid * 8 + ct) * 16;
    const int col = cb + lr;
    f4v al[2] = {fz4(), fz4()}, ar_[2] = {fz4(), fz4()};
    const unsigned short* bl = UflB + col * 512 + lg * 8;
    const unsigned short* br = UfrB + col * 512 + lg * 8;
#pragma unroll 4
    for (int k0 = 0; k0 < 16; ++k0) {
      s8v vbl = *(const s8v*)(bl + k0 * 32);
      s8v vbr = *(const s8v*)(br + k0 * 32);
#pragma unroll
      for (int mt = 0; mt < 2; ++mt) {
        int arow = mt * 16 + lr;
        int byte = arow * 1024 + (k0 * 32 + lg * 8) * 2;
        byte ^= ((arow >> 1) & 7) << 4;
        s8v a = *(const s8v*)((char*)chh + byte);
        al[mt]  = __builtin_amdgcn_mfma_f32_16x16x32_bf16(a, vbl, al[mt], 0, 0, 0);
        ar_[mt] = __builtin_amdgcn_mfma_f32_16x16x32_bf16(a, vbr, ar_[mt], 0, 0, 0);
      }
    }
#pragma unroll
    for (int mt = 0; mt < 2; ++mt) {
      float fc[4];
#pragma unroll
      for (int r = 0; r < 4; ++r) {
        int j = mt * 16 + lg * 4 + r;
        int pl = j >> 1;
        int p = pb * 16 + pl;
        float fcv = 0.f;
        if (p < P) {
          int t = p >> shift, k = p & nmask;
          int pg = t * PER_ + start_l + k;
          int cg = t * PER_ + start_lm1 + 2 * k + (j & 1);
          float wf = bf2f(PRE[(size_t)pg * 2048 + 1536 + col]);
          float cc = c_out[(size_t)cg * 512 + col];
          fcv = (sigm(wf + al[mt][r]) + sigm(wf + ar_[mt][r])) * cc;
        }
        fc[r] = fcv;
      }
      int plo = mt * 8 + lg * 2;
      fcsum[plo * 512 + col]       = fc[0] + fc[1];
      fcsum[(plo + 1) * 512 + col] = fc[2] + fc[3];
    }
  }
  __syncthreads();
  for (int ct = 0; ct < 8; ++ct) {
    const int cb = (wid * 8 + ct) * 16;
    const int col = cb + lr;
    f4v ai = fz4(), ao = fz4(), au = fz4();
    const unsigned short* bi = Ucat + (size_t)col * 1024 + lg * 8;
    const unsigned short* bo = Ucat + (size_t)(512 + col) * 1024 + lg * 8;
    const unsigned short* bu = Ucat + (size_t)(1024 + col) * 1024 + lg * 8;
#pragma unroll 2
    for (int k0 = 0; k0 < 32; ++k0) {
      int kk = k0 * 32 + lg * 8;
      int a2row = (lr << 1) | (kk >> 9);
      int a2col = kk & 511;
      int byte = a2row * 1024 + a2col * 2;
      byte ^= ((a2row >> 1) & 7) << 4;
      s8v a = *(const s8v*)((char*)chh + byte);
      s8v vi = *(const s8v*)(bi + k0 * 32);
      s8v vo = *(const s8v*)(bo + k0 * 32);
      s8v vu = *(const s8v*)(bu + k0 * 32);
      ai = __builtin_amdgcn_mfma_f32_16x16x32_bf16(a, vi, ai, 0, 0, 0);
      ao = __builtin_amdgcn_mfma_f32_16x16x32_bf16(a, vo, ao, 0, 0, 0);
      au = __builtin_amdgcn_mfma_f32_16x16x32_bf16(a, vu, au, 0, 0, 0);
    }
#pragma unroll
    for (int r = 0; r < 4; ++r) {
      int pl = lg * 4 + r;
      int p = pb * 16 + pl;
      if (p < P) {
        int t = p >> shift, k = p & nmask;
        int pg = t * PER_ + start_l + k;
        float iv = ai[r] + bf2f(PRE[(size_t)pg * 2048 + col]);
        float ov = ao[r] + bf2f(PRE[(size_t)pg * 2048 + 512 + col]);
        float uv = au[r] + bf2f(PRE[(size_t)pg * 2048 + 1024 + col]);
        float cvv = sigm(iv) * tanh_s(uv) + fcsum[pl * 512 + col];
        float hvv = sigm(ov) * tanh_s(cvv);
        h_out[(size_t)pg * 512 + col] = hvv;
        c_out[(size_t)pg * 512 + col] = cvv;
        HB[(size_t)pg * 512 + col] = f2bf(hvv);
      }
    }
  }
}

__global__ void fill_sentinel(float* out, int n) {
  int i = blockIdx.x * 256 + threadIdx.x;
  if (i < n) out[i] = 12345.0f;
}

// ---------------- host launch -------------------------------------------
extern "C" void kernel_launch(void* const* d_in, const int* in_sizes, int n_in,
                              void* d_out, int out_size, void* d_ws, size_t ws_size,
                              hipStream_t stream) {
  (void)in_sizes; (void)n_in; (void)out_size;
  const float* feat = (const float*)d_in[0];
  const float* Wiou = (const float*)d_in[4];
  const float* biou = (const float*)d_in[5];
  const float* Ul   = (const float*)d_in[6];
  const float* Ur   = (const float*)d_in[7];
  const float* Wf   = (const float*)d_in[8];
  const float* bfb  = (const float*)d_in[9];
  const float* Ufl  = (const float*)d_in[10];
  const float* Ufr  = (const float*)d_in[11];
  float* h_out = (float*)d_out;
  float* c_out = h_out + (size_t)NN_ * 512;

  const size_t OFF_PRE  = 0;
  const size_t SZ_PRE   = (size_t)NN_ * 2048 * 2;
  const size_t OFF_HB   = OFF_PRE + SZ_PRE;
  const size_t SZ_HB    = (size_t)NN_ * 512 * 2;
  const size_t OFF_WCAT = OFF_HB + SZ_HB;
  const size_t SZ_WCAT  = 2048 * 512 * 2;
  const size_t OFF_UCAT = OFF_WCAT + SZ_WCAT;
  const size_t SZ_UCAT  = 1536 * 1024 * 2;
  const size_t OFF_UFL  = OFF_UCAT + SZ_UCAT;
  const size_t SZ_UF    = 512 * 512 * 2;
  const size_t OFF_UFR  = OFF_UFL + SZ_UF;
  const size_t OFF_UFLR = OFF_UFR + SZ_UF;
  const size_t SZ_UFLR  = 1024 * 512 * 2;
  const size_t OFF_IOU  = OFF_UFLR + SZ_UFLR;
  const size_t SZ_IOU   = (size_t)25600 * 1536 * 2;   // level-1 P, reused
  const size_t NEEDED   = OFF_IOU + SZ_IOU;

  if (ws_size < NEEDED) {
    int n = 2 * NN_ * 512;
    fill_sentinel<<<(n + 255) / 256, 256, 0, stream>>>((float*)d_out, n);
    return;
  }

  char* ws = (char*)d_ws;
  unsigned short* PRE  = (unsigned short*)(ws + OFF_PRE);
  unsigned short* HB   = (unsigned short*)(ws + OFF_HB);
  unsigned short* WCAT = (unsigned short*)(ws + OFF_WCAT);
  unsigned short* UCAT = (unsigned short*)(ws + OFF_UCAT);
  unsigned short* UFLB = (unsigned short*)(ws + OFF_UFL);
  unsigned short* UFRB = (unsigned short*)(ws + OFF_UFR);
  unsigned short* UFLR = (unsigned short*)(ws + OFF_UFLR);
  unsigned short* IOU  = (unsigned short*)(ws + OFF_IOU);

  prep_weights<<<6144, 256, 0, stream>>>(Wiou, Wf, Ul, Ur, Ufl, Ufr,
                                         WCAT, UCAT, UFLB, UFRB, UFLR);
  {
    int tm = (NN_ + 127) / 128;            // 800
    pre_gemm<<<tm * 16, 256, 0, stream>>>(feat, WCAT, biou, bfb, PRE);
  }
  leaf_kernel<<<(TREES_ * 1024 * 128) / 256, 256, 0, stream>>>(PRE, h_out, c_out, HB);

  for (int l = 1; l <= 10; ++l) {
    int shift = 10 - l;
    int P = TREES_ << shift;
    int start_l   = 2048 - (1 << (11 - l));
    int start_lm1 = 2048 - (1 << (12 - l));
    if (l <= 5) {
      int m2tiles = (2 * P) / 128;          // exact for l<=5
      g1_kernel<<<m2tiles * 8, 256, 0, stream>>>(HB, UFLR, PRE, c_out, h_out,
                                                 shift, start_l, start_lm1);
      int mtiles = (P + 127) / 128;
      g2_kernel<<<mtiles * 12, 256, 0, stream>>>(HB, UCAT, PRE, IOU,
                                                 P, shift, start_l, start_lm1);
      int g3b = (P * 128 + 255) / 256;
      g3_kernel<<<g3b, 256, 0, stream>>>(IOU, h_out, c_out, HB, P, shift, start_l);
    } else {
      int gb = (P + 15) / 16;
      level_kernel<<<gb, 256, 0, stream>>>(PRE, UCAT, UFLB, UFRB,
                                           h_out, c_out, HB,
                                           P, shift, start_l, start_lm1);
    }
  }
}

// Round 4
// 2111.841 us; speedup vs baseline: 1.6697x; 1.2307x over previous
//
#include <hip/hip_runtime.h>
#include <hip/hip_bf16.h>

#define TREES_ 50
#define PER_ 2047
#define NN_ (TREES_ * PER_)   // 102350 nodes

typedef __attribute__((ext_vector_type(8))) short s8v;   // 8 bf16
typedef __attribute__((ext_vector_type(4))) float f4v;   // MFMA C/D

__device__ __forceinline__ unsigned short f2bf(float f) {
  union { float f; unsigned u; } v; v.f = f;
  unsigned r = v.u + 0x7FFFu + ((v.u >> 16) & 1u);   // RNE
  return (unsigned short)(r >> 16);
}
__device__ __forceinline__ float bf2f(unsigned short s) {
  union { unsigned u; float f; } v; v.u = ((unsigned)s) << 16;
  return v.f;
}
__device__ __forceinline__ float sigm(float x) { return 1.f / (1.f + __expf(-x)); }
__device__ __forceinline__ float tanh_s(float x) {
  float ax = fabsf(x);
  float e = __expf(2.f * ax);
  float t = 1.f - 2.f / (e + 1.f);
  return copysignf(t, x);
}
__device__ __forceinline__ f4v fz4() { f4v z; z[0]=0.f; z[1]=0.f; z[2]=0.f; z[3]=0.f; return z; }

// async global->LDS, 16B per lane; LDS dest = wave-uniform base + lane*16
#if defined(__has_builtin)
#if __has_builtin(__builtin_amdgcn_global_load_lds)
#define HAS_GLD 1
#endif
#endif
__device__ __forceinline__ void gld16(const void* g, void* l) {
#ifdef HAS_GLD
  __builtin_amdgcn_global_load_lds(
      (const __attribute__((address_space(1))) unsigned int*)g,
      (__attribute__((address_space(3))) unsigned int*)l, 16, 0, 0);
#else
  *(s8v*)l = *(const s8v*)g;
#endif
}

// bijective XCD-chunked swizzle (m204): same-M-tile blocks land on one XCD
__device__ __forceinline__ int xcd_swz(int bid, int nwg) {
  int q = nwg >> 3, r = nwg & 7, x = bid & 7, pos = bid >> 3;
  int base = (x < r) ? x * (q + 1) : r * (q + 1) + (x - r) * q;
  return base + pos;
}

// LDS tile [128 rows][64 bf16]: logical chunk (row,c16) lives at swizzled byte
#define LDS_BYTE(row, c16) ((row) * 128 + (((c16) ^ ((row) & 7)) << 4))
// staging: linear slot q=(row,c16s) must receive global chunk c16g = c16s ^ (row&7)

// ---------------- feat fp32 -> bf16 --------------------------------------
__global__ __launch_bounds__(256) void feat2bf(const float* __restrict__ feat,
                                               unsigned short* __restrict__ FB) {
  long long i = (long long)blockIdx.x * 256 + threadIdx.x;   // one 8-elem chunk
  const float* src = feat + i * 8;
  float4 f0 = *(const float4*)src;
  float4 f1 = *(const float4*)(src + 4);
  s8v v;
  v[0] = (short)f2bf(f0.x); v[1] = (short)f2bf(f0.y);
  v[2] = (short)f2bf(f0.z); v[3] = (short)f2bf(f0.w);
  v[4] = (short)f2bf(f1.x); v[5] = (short)f2bf(f1.y);
  v[6] = (short)f2bf(f1.z); v[7] = (short)f2bf(f1.w);
  *(s8v*)(FB + i * 8) = v;
}

// ---------------- weight prep: fp32 -> bf16 (+concat/interleave) ---------
__global__ __launch_bounds__(256) void prep_weights(
    const float* __restrict__ Wiou, const float* __restrict__ Wf,
    const float* __restrict__ Ul,  const float* __restrict__ Ur,
    const float* __restrict__ Ufl, const float* __restrict__ Ufr,
    unsigned short* __restrict__ Wcat, unsigned short* __restrict__ Ucat,
    unsigned short* __restrict__ Uflr) {
  int i = blockIdx.x * 256 + threadIdx.x;
  if (i < 2048 * 512) {
    int r = i >> 9, c = i & 511;
    float v = (r < 1536) ? Wiou[r * 512 + c] : Wf[(r - 1536) * 512 + c];
    Wcat[i] = f2bf(v);
  }
  if (i < 1536 * 1024) {
    int r = i >> 10, c = i & 1023;
    float v = (c < 512) ? Ul[r * 512 + c] : Ur[r * 512 + (c - 512)];
    Ucat[i] = f2bf(v);
  }
  if (i < 1024 * 512) {
    int r = i >> 9, k = i & 511;
    int c = r >> 1, s = r & 1;
    Uflr[i] = f2bf(s ? Ufr[c * 512 + k] : Ufl[c * 512 + k]);
  }
}

// ---- pre GEMM: PRE[N,2048] = FB(bf16) @ Wcat^T + bias -------------------
__global__ __launch_bounds__(256) void pre_gemm(
    const unsigned short* __restrict__ FB, const unsigned short* __restrict__ Wcat,
    const float* __restrict__ biou, const float* __restrict__ bfb,
    unsigned short* __restrict__ PRE) {
  __shared__ __align__(16) unsigned short As[128 * 64];
  __shared__ __align__(16) unsigned short Bs[128 * 64];
  const int tid = threadIdx.x;
  const int swz = xcd_swz(blockIdx.x, 800 * 16);
  const int tn = swz & 15, tm = swz >> 4;
  const int wid = tid >> 6, lane = tid & 63;
  const int wr = wid >> 1, wc = wid & 1;
  const int lr = lane & 15, lg = lane >> 4;
  f4v acc[4][4];
#pragma unroll
  for (int i = 0; i < 4; ++i)
#pragma unroll
    for (int j = 0; j < 4; ++j) acc[i][j] = fz4();
  for (int k0 = 0; k0 < 512; k0 += 64) {
#pragma unroll
    for (int L = 0; L < 4; ++L) {
      int q = L * 256 + tid;
      int row = q >> 3, c16s = q & 7;
      int c16g = c16s ^ (row & 7);
      {  // A
        int g = tm * 128 + row; if (g >= NN_) g = NN_ - 1;
        gld16(FB + (size_t)g * 512 + k0 + c16g * 8, (unsigned short*)As + q * 8);
      }
      {  // B
        int n = tn * 128 + row;
        gld16(Wcat + (size_t)n * 512 + k0 + c16g * 8, (unsigned short*)Bs + q * 8);
      }
    }
    __syncthreads();
#pragma unroll
    for (int kk = 0; kk < 2; ++kk) {
      s8v af[4], bf_[4];
#pragma unroll
      for (int i = 0; i < 4; ++i) {
        int R = wr * 64 + i * 16 + lr;
        af[i] = *(const s8v*)((char*)As + LDS_BYTE(R, kk * 4 + lg));
      }
#pragma unroll
      for (int j = 0; j < 4; ++j) {
        int R = wc * 64 + j * 16 + lr;
        bf_[j] = *(const s8v*)((char*)Bs + LDS_BYTE(R, kk * 4 + lg));
      }
#pragma unroll
      for (int i = 0; i < 4; ++i)
#pragma unroll
        for (int j = 0; j < 4; ++j)
          acc[i][j] = __builtin_amdgcn_mfma_f32_16x16x32_bf16(af[i], bf_[j], acc[i][j], 0, 0, 0);
    }
    __syncthreads();
  }
#pragma unroll
  for (int i = 0; i < 4; ++i)
#pragma unroll
    for (int j = 0; j < 4; ++j) {
      int n = tn * 128 + wc * 64 + j * 16 + lr;
      float bias = (n < 1536) ? biou[n] : bfb[n - 1536];
#pragma unroll
      for (int r = 0; r < 4; ++r) {
        int m = tm * 128 + wr * 64 + i * 16 + lg * 4 + r;
        if (m < NN_) PRE[(size_t)m * 2048 + n] = f2bf(acc[i][j][r] + bias);
      }
    }
}

// ---- G1: f-gate GEMM [2P,512] @ Uflr^T, fused fc; fcsum -> h_out --------
__global__ __launch_bounds__(256) void g1_kernel(
    const unsigned short* __restrict__ HB, const unsigned short* __restrict__ Uflr,
    const unsigned short* __restrict__ PRE, const float* __restrict__ c_out,
    float* __restrict__ h_out,
    int P, int shift, int start_l, int start_lm1, int nwg) {
  __shared__ __align__(16) unsigned short As[128 * 64];
  __shared__ __align__(16) unsigned short Bs[128 * 64];
  const int tid = threadIdx.x;
  const int swz = xcd_swz(blockIdx.x, nwg);
  const int tn = swz & 7, tm = swz >> 3;
  const int M2 = 2 * P;
  const int cmask = (2 << shift) - 1;
  const int wid = tid >> 6, lane = tid & 63;
  const int wr = wid >> 1, wc = wid & 1;
  const int lr = lane & 15, lg = lane >> 4;
  f4v acc[4][4];
#pragma unroll
  for (int i = 0; i < 4; ++i)
#pragma unroll
    for (int j = 0; j < 4; ++j) acc[i][j] = fz4();
  for (int k0 = 0; k0 < 512; k0 += 64) {
#pragma unroll
    for (int L = 0; L < 4; ++L) {
      int q = L * 256 + tid;
      int row = q >> 3, c16s = q & 7;
      int c16g = c16s ^ (row & 7);
      {  // A: child h rows
        int jg = tm * 128 + row; if (jg >= M2) jg = M2 - 1;
        int t = jg >> (shift + 1), idx = jg & cmask;
        gld16(HB + (size_t)(t * PER_ + start_lm1 + idx) * 512 + k0 + c16g * 8,
              (unsigned short*)As + q * 8);
      }
      {  // B
        int n = tn * 128 + row;
        gld16(Uflr + (size_t)n * 512 + k0 + c16g * 8, (unsigned short*)Bs + q * 8);
      }
    }
    __syncthreads();
#pragma unroll
    for (int kk = 0; kk < 2; ++kk) {
      s8v af[4], bf_[4];
#pragma unroll
      for (int i = 0; i < 4; ++i) {
        int R = wr * 64 + i * 16 + lr;
        af[i] = *(const s8v*)((char*)As + LDS_BYTE(R, kk * 4 + lg));
      }
#pragma unroll
      for (int j = 0; j < 4; ++j) {
        int R = wc * 64 + j * 16 + lr;
        bf_[j] = *(const s8v*)((char*)Bs + LDS_BYTE(R, kk * 4 + lg));
      }
#pragma unroll
      for (int i = 0; i < 4; ++i)
#pragma unroll
        for (int j = 0; j < 4; ++j)
          acc[i][j] = __builtin_amdgcn_mfma_f32_16x16x32_bf16(af[i], bf_[j], acc[i][j], 0, 0, 0);
    }
    __syncthreads();
  }
  const int pmask = (1 << shift) - 1;
#pragma unroll
  for (int i = 0; i < 4; ++i) {
    int mbase = tm * 128 + wr * 64 + i * 16;   // even
#pragma unroll
    for (int j = 0; j < 4; ++j) {
      int nn = tn * 128 + wc * 64 + j * 16 + lr;
      int hcol = nn >> 1;
      float fc[4];
#pragma unroll
      for (int r = 0; r < 4; ++r) {
        int m = mbase + lg * 4 + r;            // child index
        int mm = (m < M2) ? m : 0;
        int pidx = mm >> 1;
        int t = pidx >> shift, k = pidx & pmask;
        float wf = bf2f(PRE[(size_t)(t * PER_ + start_l + k) * 2048 + 1536 + hcol]);
        float sv = sigm(wf + acc[i][j][r]);
        float spair = sv + __shfl_xor(sv, 1, 64);
        float cc = 0.f;
        if ((lr & 1) == 0)
          cc = c_out[(size_t)(t * PER_ + start_lm1 + (mm & cmask)) * 512 + hcol];
        fc[r] = spair * cc;
      }
      if ((lr & 1) == 0) {
        int p0 = (mbase >> 1) + lg * 2;
        if (p0 < P) {
          int t0 = p0 >> shift, k0p = p0 & pmask;
          h_out[(size_t)(t0 * PER_ + start_l + k0p) * 512 + hcol] = fc[0] + fc[1];
        }
        int p1 = (mbase >> 1) + lg * 2 + 1;
        if (p1 < P) {
          int t1 = p1 >> shift, k1p = p1 & pmask;
          h_out[(size_t)(t1 * PER_ + start_l + k1p) * 512 + hcol] = fc[2] + fc[3];
        }
      }
    }
  }
}

// ---- G2: iou GEMM [P,1024] @ Ucat^T + PRE -> IOU (bf16) -----------------
__global__ __launch_bounds__(256) void g2_kernel(
    const unsigned short* __restrict__ HB, const unsigned short* __restrict__ Ucat,
    const unsigned short* __restrict__ PRE, unsigned short* __restrict__ IOU,
    int P, int shift, int start_l, int start_lm1, int nwg) {
  __shared__ __align__(16) unsigned short As[128 * 64];
  __shared__ __align__(16) unsigned short Bs[128 * 64];
  const int tid = threadIdx.x;
  const int swz = xcd_swz(blockIdx.x, nwg);
  const int tn = swz % 12, tm = swz / 12;
  const int pmask = (1 << shift) - 1;
  const int wid = tid >> 6, lane = tid & 63;
  const int wr = wid >> 1, wc = wid & 1;
  const int lr = lane & 15, lg = lane >> 4;
  f4v acc[4][4];
#pragma unroll
  for (int i = 0; i < 4; ++i)
#pragma unroll
    for (int j = 0; j < 4; ++j) acc[i][j] = fz4();
  for (int k0 = 0; k0 < 1024; k0 += 64) {
#pragma unroll
    for (int L = 0; L < 4; ++L) {
      int q = L * 256 + tid;
      int row = q >> 3, c16s = q & 7;
      int c16g = c16s ^ (row & 7);
      {  // A: [hl|hr] row (children contiguous in HB)
        int p = tm * 128 + row; if (p >= P) p = P - 1;
        int t = p >> shift, k = p & pmask;
        gld16(HB + (size_t)(t * PER_ + start_lm1) * 512 + (size_t)k * 1024 + k0 + c16g * 8,
              (unsigned short*)As + q * 8);
      }
      {  // B
        int n = tn * 128 + row;
        gld16(Ucat + (size_t)n * 1024 + k0 + c16g * 8, (unsigned short*)Bs + q * 8);
      }
    }
    __syncthreads();
#pragma unroll
    for (int kk = 0; kk < 2; ++kk) {
      s8v af[4], bf_[4];
#pragma unroll
      for (int i = 0; i < 4; ++i) {
        int R = wr * 64 + i * 16 + lr;
        af[i] = *(const s8v*)((char*)As + LDS_BYTE(R, kk * 4 + lg));
      }
#pragma unroll
      for (int j = 0; j < 4; ++j) {
        int R = wc * 64 + j * 16 + lr;
        bf_[j] = *(const s8v*)((char*)Bs + LDS_BYTE(R, kk * 4 + lg));
      }
#pragma unroll
      for (int i = 0; i < 4; ++i)
#pragma unroll
        for (int j = 0; j < 4; ++j)
          acc[i][j] = __builtin_amdgcn_mfma_f32_16x16x32_bf16(af[i], bf_[j], acc[i][j], 0, 0, 0);
    }
    __syncthreads();
  }
#pragma unroll
  for (int i = 0; i < 4; ++i)
#pragma unroll
    for (int j = 0; j < 4; ++j) {
      int n = tn * 128 + wc * 64 + j * 16 + lr;
#pragma unroll
      for (int r = 0; r < 4; ++r) {
        int m = tm * 128 + wr * 64 + i * 16 + lg * 4 + r;
        if (m < P) {
          int t = m >> shift, k = m & pmask;
          size_t pg = (size_t)(t * PER_ + start_l + k);
          IOU[(size_t)m * 1536 + n] = f2bf(acc[i][j][r] + bf2f(PRE[pg * 2048 + n]));
        }
      }
    }
}

// ---- G3: elementwise combine; reads fcsum from h_out, overwrites with h -
__global__ __launch_bounds__(256) void g3_kernel(
    const unsigned short* __restrict__ IOU,
    float* __restrict__ h_out, float* __restrict__ c_out,
    unsigned short* __restrict__ HB, int P, int shift, int start_l) {
  int idx = blockIdx.x * 256 + threadIdx.x;
  int p = idx >> 7;
  if (p >= P) return;
  int c4 = (idx & 127) << 2;
  int t = p >> shift, k = p & ((1 << shift) - 1);
  size_t pg = (size_t)(t * PER_ + start_l + k);
  const unsigned short* ir = IOU + (size_t)p * 1536;
  ushort4 iv = *(const ushort4*)(ir + c4);
  ushort4 ov = *(const ushort4*)(ir + 512 + c4);
  ushort4 uv = *(const ushort4*)(ir + 1024 + c4);
  float4 fcs = *(const float4*)(h_out + pg * 512 + c4);
  float4 hv, cv; ushort4 hb;
  float cc, hh;
  cc = sigm(bf2f(iv.x)) * tanh_s(bf2f(uv.x)) + fcs.x; hh = sigm(bf2f(ov.x)) * tanh_s(cc);
  cv.x = cc; hv.x = hh; hb.x = f2bf(hh);
  cc = sigm(bf2f(iv.y)) * tanh_s(bf2f(uv.y)) + fcs.y; hh = sigm(bf2f(ov.y)) * tanh_s(cc);
  cv.y = cc; hv.y = hh; hb.y = f2bf(hh);
  cc = sigm(bf2f(iv.z)) * tanh_s(bf2f(uv.z)) + fcs.z; hh = sigm(bf2f(ov.z)) * tanh_s(cc);
  cv.z = cc; hv.z = hh; hb.z = f2bf(hh);
  cc = sigm(bf2f(iv.w)) * tanh_s(bf2f(uv.w)) + fcs.w; hh = sigm(bf2f(ov.w)) * tanh_s(cc);
  cv.w = cc; hv.w = hh; hb.w = f2bf(hh);
  *(float4*)(h_out + pg * 512 + c4) = hv;
  *(float4*)(c_out + pg * 512 + c4) = cv;
  *(ushort4*)(HB + pg * 512 + c4) = hb;
}

// ---------------- leaves: pure elementwise from PRE ----------------------
__global__ __launch_bounds__(256) void leaf_kernel(
    const unsigned short* __restrict__ PRE,
    float* __restrict__ h_out, float* __restrict__ c_out,
    unsigned short* __restrict__ HB) {
  int idx = blockIdx.x * 256 + threadIdx.x;
  int r = idx >> 7;
  int c4 = (idx & 127) << 2;
  int t = r >> 10, li = r & 1023;
  int g = t * PER_ + li;
  const unsigned short* pr = PRE + (size_t)g * 2048;
  ushort4 iv = *(const ushort4*)(pr + c4);
  ushort4 ov = *(const ushort4*)(pr + 512 + c4);
  ushort4 uv = *(const ushort4*)(pr + 1024 + c4);
  float4 hv, cv; ushort4 hb;
  float cc, hh;
  cc = sigm(bf2f(iv.x)) * tanh_s(bf2f(uv.x)); hh = sigm(bf2f(ov.x)) * tanh_s(cc);
  cv.x = cc; hv.x = hh; hb.x = f2bf(hh);
  cc = sigm(bf2f(iv.y)) * tanh_s(bf2f(uv.y)); hh = sigm(bf2f(ov.y)) * tanh_s(cc);
  cv.y = cc; hv.y = hh; hb.y = f2bf(hh);
  cc = sigm(bf2f(iv.z)) * tanh_s(bf2f(uv.z)); hh = sigm(bf2f(ov.z)) * tanh_s(cc);
  cv.z = cc; hv.z = hh; hb.z = f2bf(hh);
  cc = sigm(bf2f(iv.w)) * tanh_s(bf2f(uv.w)); hh = sigm(bf2f(ov.w)) * tanh_s(cc);
  cv.w = cc; hv.w = hh; hb.w = f2bf(hh);
  *(float4*)(h_out + (size_t)g * 512 + c4) = hv;
  *(float4*)(c_out + (size_t)g * 512 + c4) = cv;
  *(ushort4*)(HB + (size_t)g * 512 + c4) = hb;
}

__global__ void fill_sentinel(float* out, int n) {
  int i = blockIdx.x * 256 + threadIdx.x;
  if (i < n) out[i] = 12345.0f;
}

// ---------------- host launch -------------------------------------------
extern "C" void kernel_launch(void* const* d_in, const int* in_sizes, int n_in,
                              void* d_out, int out_size, void* d_ws, size_t ws_size,
                              hipStream_t stream) {
  (void)in_sizes; (void)n_in; (void)out_size;
  const float* feat = (const float*)d_in[0];
  const float* Wiou = (const float*)d_in[4];
  const float* biou = (const float*)d_in[5];
  const float* Ul   = (const float*)d_in[6];
  const float* Ur   = (const float*)d_in[7];
  const float* Wf   = (const float*)d_in[8];
  const float* bfb  = (const float*)d_in[9];
  const float* Ufl  = (const float*)d_in[10];
  const float* Ufr  = (const float*)d_in[11];
  float* h_out = (float*)d_out;
  float* c_out = h_out + (size_t)NN_ * 512;

  const size_t OFF_PRE  = 0;
  const size_t SZ_PRE   = (size_t)NN_ * 2048 * 2;         // 419.2 MB
  const size_t OFF_HB   = OFF_PRE + SZ_PRE;
  const size_t SZ_HB    = (size_t)NN_ * 512 * 2;          // 104.8 MB
  const size_t OFF_WCAT = OFF_HB + SZ_HB;
  const size_t SZ_WCAT  = 2048 * 512 * 2;
  const size_t OFF_UCAT = OFF_WCAT + SZ_WCAT;
  const size_t SZ_UCAT  = 1536 * 1024 * 2;
  const size_t OFF_UFLR = OFF_UCAT + SZ_UCAT;
  const size_t SZ_UFLR  = 1024 * 512 * 2;
  const size_t OFF_FBIO = OFF_UFLR + SZ_UFLR;             // FB and IOU alias
  const size_t SZ_FB    = (size_t)NN_ * 512 * 2;          // 104.8 MB (>= IOU 78.6)
  const size_t NEEDED   = OFF_FBIO + SZ_FB;

  if (ws_size < NEEDED) {
    int n = 2 * NN_ * 512;
    fill_sentinel<<<(n + 255) / 256, 256, 0, stream>>>((float*)d_out, n);
    return;
  }

  char* ws = (char*)d_ws;
  unsigned short* PRE  = (unsigned short*)(ws + OFF_PRE);
  unsigned short* HB   = (unsigned short*)(ws + OFF_HB);
  unsigned short* WCAT = (unsigned short*)(ws + OFF_WCAT);
  unsigned short* UCAT = (unsigned short*)(ws + OFF_UCAT);
  unsigned short* UFLR = (unsigned short*)(ws + OFF_UFLR);
  unsigned short* FB   = (unsigned short*)(ws + OFF_FBIO);
  unsigned short* IOU  = (unsigned short*)(ws + OFF_FBIO);

  prep_weights<<<6144, 256, 0, stream>>>(Wiou, Wf, Ul, Ur, Ufl, Ufr,
                                         WCAT, UCAT, UFLR);
  feat2bf<<<(NN_ * 512 / 8 + 255) / 256, 256, 0, stream>>>(feat, FB);
  pre_gemm<<<800 * 16, 256, 0, stream>>>(FB, WCAT, biou, bfb, PRE);
  leaf_kernel<<<(TREES_ * 1024 * 128) / 256, 256, 0, stream>>>(PRE, h_out, c_out, HB);

  for (int l = 1; l <= 10; ++l) {
    int shift = 10 - l;
    int P = TREES_ << shift;
    int start_l   = 2048 - (1 << (11 - l));
    int start_lm1 = 2048 - (1 << (12 - l));
    int m2tiles = (2 * P + 127) / 128;
    int nwg1 = m2tiles * 8;
    g1_kernel<<<nwg1, 256, 0, stream>>>(HB, UFLR, PRE, c_out, h_out,
                                        P, shift, start_l, start_lm1, nwg1);
    int mtiles = (P + 127) / 128;
    int nwg2 = mtiles * 12;
    g2_kernel<<<nwg2, 256, 0, stream>>>(HB, UCAT, PRE, IOU,
                                        P, shift, start_l, start_lm1, nwg2);
    int g3b = (P * 128 + 255) / 256;
    g3_kernel<<<g3b, 256, 0, stream>>>(IOU, h_out, c_out, HB, P, shift, start_l);
  }
}

// Round 5
// 1498.879 us; speedup vs baseline: 2.3525x; 1.4089x over previous
//
#include <hip/hip_runtime.h>
#include <hip/hip_bf16.h>

#define TREES_ 50
#define PER_ 2047
#define NN_ (TREES_ * PER_)      // 102350 nodes
#define NINT_ (TREES_ * 1023)    // 51150 internal nodes
#define NLEAF_ (TREES_ * 1024)   // 51200 leaves

typedef __attribute__((ext_vector_type(8))) short s8v;   // 8 bf16
typedef __attribute__((ext_vector_type(4))) float f4v;   // MFMA C/D

__device__ __forceinline__ unsigned short f2bf(float f) {
  union { float f; unsigned u; } v; v.f = f;
  unsigned r = v.u + 0x7FFFu + ((v.u >> 16) & 1u);   // RNE
  return (unsigned short)(r >> 16);
}
__device__ __forceinline__ float bf2f(unsigned short s) {
  union { unsigned u; float f; } v; v.u = ((unsigned)s) << 16;
  return v.f;
}
__device__ __forceinline__ float sigm(float x) { return 1.f / (1.f + __expf(-x)); }
__device__ __forceinline__ float tanh_s(float x) {
  float ax = fabsf(x);
  float e = __expf(2.f * ax);
  float t = 1.f - 2.f / (e + 1.f);
  return copysignf(t, x);
}
__device__ __forceinline__ f4v fz4() { f4v z; z[0]=0.f; z[1]=0.f; z[2]=0.f; z[3]=0.f; return z; }

#if defined(__has_builtin)
#if __has_builtin(__builtin_amdgcn_global_load_lds)
#define HAS_GLD 1
#endif
#endif
__device__ __forceinline__ void gld16(const void* g, void* l) {
#ifdef HAS_GLD
  __builtin_amdgcn_global_load_lds(
      (const __attribute__((address_space(1))) unsigned int*)g,
      (__attribute__((address_space(3))) unsigned int*)l, 16, 0, 0);
#else
  *(s8v*)l = *(const s8v*)g;
#endif
}

// bijective XCD-chunked swizzle (m204)
__device__ __forceinline__ int xcd_swz(int bid, int nwg) {
  int q = nwg >> 3, r = nwg & 7, x = bid & 7, pos = bid >> 3;
  int base = (x < r) ? x * (q + 1) : r * (q + 1) + (x - r) * q;
  return base + pos;
}

// LDS tile [128 rows][64 bf16]; logical chunk (row,c16) at swizzled byte.
// Staging writes LINEAR slot q=(row,c16s) from global chunk c16g=c16s^(row&7).
#define LDS_BYTE(row, c16) ((row) * 128 + (((c16) ^ ((row) & 7)) << 4))

// inner compute: one K-step (64) of 128x128 tile, 4 waves
#define MFMA_STEP(As, Bs)                                                     \
  for (int kk = 0; kk < 2; ++kk) {                                            \
    s8v af[4], bf_[4];                                                        \
    _Pragma("unroll") for (int i = 0; i < 4; ++i) {                           \
      int R = wr * 64 + i * 16 + lr;                                          \
      af[i] = *(const s8v*)((char*)As + LDS_BYTE(R, kk * 4 + lg));            \
    }                                                                         \
    _Pragma("unroll") for (int j = 0; j < 4; ++j) {                           \
      int R = wc * 64 + j * 16 + lr;                                          \
      bf_[j] = *(const s8v*)((char*)Bs + LDS_BYTE(R, kk * 4 + lg));           \
    }                                                                         \
    _Pragma("unroll") for (int i = 0; i < 4; ++i)                             \
      _Pragma("unroll") for (int j = 0; j < 4; ++j)                           \
        acc[i][j] = __builtin_amdgcn_mfma_f32_16x16x32_bf16(af[i], bf_[j],    \
                                                            acc[i][j], 0, 0, 0); \
  }

// ---------------- feat fp32 -> bf16 --------------------------------------
__global__ __launch_bounds__(256) void feat2bf(const float* __restrict__ feat,
                                               unsigned short* __restrict__ FB) {
  long long i = (long long)blockIdx.x * 256 + threadIdx.x;
  if (i >= (long long)NN_ * 64) return;   // guard (R4 bug fix)
  const float* src = feat + i * 8;
  float4 f0 = *(const float4*)src;
  float4 f1 = *(const float4*)(src + 4);
  s8v v;
  v[0] = (short)f2bf(f0.x); v[1] = (short)f2bf(f0.y);
  v[2] = (short)f2bf(f0.z); v[3] = (short)f2bf(f0.w);
  v[4] = (short)f2bf(f1.x); v[5] = (short)f2bf(f1.y);
  v[6] = (short)f2bf(f1.z); v[7] = (short)f2bf(f1.w);
  *(s8v*)(FB + i * 8) = v;
}

// -------- weight prep --------
// UCAT2 [1536][1536]: row n = [U_iou_l[n] | U_iou_r[n] | W_iou[n]]
// UFLR  [1024][512]:  row 2c=Ufl[c], 2c+1=Ufr[c]
// WFB   [512][512]:   W_f
__global__ __launch_bounds__(256) void prep_weights(
    const float* __restrict__ Wiou, const float* __restrict__ Ul,
    const float* __restrict__ Ur,  const float* __restrict__ Wf,
    const float* __restrict__ Ufl, const float* __restrict__ Ufr,
    unsigned short* __restrict__ UCAT2, unsigned short* __restrict__ UFLR,
    unsigned short* __restrict__ WFB) {
  int i = blockIdx.x * 256 + threadIdx.x;
  if (i < 1536 * 1536) {
    int r = i / 1536, c = i - r * 1536;
    float v = (c < 512) ? Ul[r * 512 + c]
            : (c < 1024) ? Ur[r * 512 + (c - 512)]
                         : Wiou[r * 512 + (c - 1024)];
    UCAT2[i] = f2bf(v);
  }
  if (i < 1024 * 512) {
    int r = i >> 9, k = i & 511;
    int c = r >> 1, s = r & 1;
    UFLR[i] = f2bf(s ? Ufr[c * 512 + k] : Ufl[c * 512 + k]);
  }
  if (i < 512 * 512) WFB[i] = f2bf(Wf[i]);
}

// ---- WF GEMM: WF[51150,512] = FB(internal) @ W_f^T + b_f ----------------
__global__ __launch_bounds__(256) void wf_gemm(
    const unsigned short* __restrict__ FB, const unsigned short* __restrict__ WFB,
    const float* __restrict__ bfb, unsigned short* __restrict__ WF, int nwg) {
  __shared__ __align__(16) unsigned short As[128 * 64];
  __shared__ __align__(16) unsigned short Bs[128 * 64];
  const int tid = threadIdx.x;
  const int swz = xcd_swz(blockIdx.x, nwg);
  const int tn = swz & 3, tm = swz >> 2;
  const int wid = tid >> 6, lane = tid & 63;
  const int wr = wid >> 1, wc = wid & 1;
  const int lr = lane & 15, lg = lane >> 4;
  // precompute per-L source bases (row fixed across K)
  const unsigned short* aA[4]; const unsigned short* aB[4];
#pragma unroll
  for (int L = 0; L < 4; ++L) {
    int q = L * 256 + tid;
    int row = q >> 3, c16g = (q & 7) ^ (row & 7);
    int m = tm * 128 + row; if (m >= NINT_) m = NINT_ - 1;
    unsigned t = (unsigned)m / 1023u;
    int node = (int)t * 2047 + 1024 + (m - (int)t * 1023);
    aA[L] = FB + (size_t)node * 512 + c16g * 8;
    int n = tn * 128 + row;
    aB[L] = WFB + (size_t)n * 512 + c16g * 8;
  }
  f4v acc[4][4];
#pragma unroll
  for (int i = 0; i < 4; ++i)
#pragma unroll
    for (int j = 0; j < 4; ++j) acc[i][j] = fz4();
  for (int k0 = 0; k0 < 512; k0 += 64) {
#pragma unroll
    for (int L = 0; L < 4; ++L) {
      int q = L * 256 + tid;
      gld16(aA[L] + k0, (unsigned short*)As + q * 8);
      gld16(aB[L] + k0, (unsigned short*)Bs + q * 8);
    }
    __syncthreads();
    MFMA_STEP(As, Bs)
    __syncthreads();
  }
#pragma unroll
  for (int i = 0; i < 4; ++i)
#pragma unroll
    for (int j = 0; j < 4; ++j) {
      int n = tn * 128 + wc * 64 + j * 16 + lr;
      float bias = bfb[n];
#pragma unroll
      for (int r = 0; r < 4; ++r) {
        int m = tm * 128 + wr * 64 + i * 16 + lg * 4 + r;
        if (m < NINT_) WF[(size_t)m * 512 + n] = f2bf(acc[i][j][r] + bias);
      }
    }
}

// ---- leaf GEMM: LIOU[51200,1536] = FB(leaves) @ W_iou^T + b_iou ---------
__global__ __launch_bounds__(256) void leaf_gemm(
    const unsigned short* __restrict__ FB, const unsigned short* __restrict__ UCAT2,
    const float* __restrict__ biou, unsigned short* __restrict__ LIOU, int nwg) {
  __shared__ __align__(16) unsigned short As[128 * 64];
  __shared__ __align__(16) unsigned short Bs[128 * 64];
  const int tid = threadIdx.x;
  const int swz = xcd_swz(blockIdx.x, nwg);
  const int tn = swz % 12, tm = swz / 12;
  const int wid = tid >> 6, lane = tid & 63;
  const int wr = wid >> 1, wc = wid & 1;
  const int lr = lane & 15, lg = lane >> 4;
  const unsigned short* aA[4]; const unsigned short* aB[4];
#pragma unroll
  for (int L = 0; L < 4; ++L) {
    int q = L * 256 + tid;
    int row = q >> 3, c16g = (q & 7) ^ (row & 7);
    int m = tm * 128 + row;                       // leaf-linear (exact: 51200%128==0)
    int node = (m >> 10) * 2047 + (m & 1023);
    aA[L] = FB + (size_t)node * 512 + c16g * 8;
    int n = tn * 128 + row;
    aB[L] = UCAT2 + (size_t)n * 1536 + 1024 + c16g * 8;  // W_iou slice
  }
  f4v acc[4][4];
#pragma unroll
  for (int i = 0; i < 4; ++i)
#pragma unroll
    for (int j = 0; j < 4; ++j) acc[i][j] = fz4();
  for (int k0 = 0; k0 < 512; k0 += 64) {
#pragma unroll
    for (int L = 0; L < 4; ++L) {
      int q = L * 256 + tid;
      gld16(aA[L] + k0, (unsigned short*)As + q * 8);
      gld16(aB[L] + k0, (unsigned short*)Bs + q * 8);
    }
    __syncthreads();
    MFMA_STEP(As, Bs)
    __syncthreads();
  }
#pragma unroll
  for (int i = 0; i < 4; ++i)
#pragma unroll
    for (int j = 0; j < 4; ++j) {
      int n = tn * 128 + wc * 64 + j * 16 + lr;
      float bias = biou[n];
#pragma unroll
      for (int r = 0; r < 4; ++r) {
        int m = tm * 128 + wr * 64 + i * 16 + lg * 4 + r;
        LIOU[(size_t)m * 1536 + n] = f2bf(acc[i][j][r] + bias);
      }
    }
}

// ---- leaf elementwise ---------------------------------------------------
__global__ __launch_bounds__(256) void leaf_ew(
    const unsigned short* __restrict__ LIOU,
    float* __restrict__ h_out, float* __restrict__ c_out,
    unsigned short* __restrict__ HB) {
  int idx = blockIdx.x * 256 + threadIdx.x;
  int r = idx >> 7;
  int c4 = (idx & 127) << 2;
  int g = (r >> 10) * 2047 + (r & 1023);
  const unsigned short* pr = LIOU + (size_t)r * 1536;
  ushort4 iv = *(const ushort4*)(pr + c4);
  ushort4 ov = *(const ushort4*)(pr + 512 + c4);
  ushort4 uv = *(const ushort4*)(pr + 1024 + c4);
  float4 hv, cv; ushort4 hb;
  float cc, hh;
  cc = sigm(bf2f(iv.x)) * tanh_s(bf2f(uv.x)); hh = sigm(bf2f(ov.x)) * tanh_s(cc);
  cv.x = cc; hv.x = hh; hb.x = f2bf(hh);
  cc = sigm(bf2f(iv.y)) * tanh_s(bf2f(uv.y)); hh = sigm(bf2f(ov.y)) * tanh_s(cc);
  cv.y = cc; hv.y = hh; hb.y = f2bf(hh);
  cc = sigm(bf2f(iv.z)) * tanh_s(bf2f(uv.z)); hh = sigm(bf2f(ov.z)) * tanh_s(cc);
  cv.z = cc; hv.z = hh; hb.z = f2bf(hh);
  cc = sigm(bf2f(iv.w)) * tanh_s(bf2f(uv.w)); hh = sigm(bf2f(ov.w)) * tanh_s(cc);
  cv.w = cc; hv.w = hh; hb.w = f2bf(hh);
  *(float4*)(h_out + (size_t)g * 512 + c4) = hv;
  *(float4*)(c_out + (size_t)g * 512 + c4) = cv;
  *(ushort4*)(HB + (size_t)g * 512 + c4) = hb;
}

// ---- merged level GEMM: bid<nwg1 -> f-gate (g1); else iou (g2) ----------
__global__ __launch_bounds__(256) void lvl_gemm(
    const unsigned short* __restrict__ HB, const unsigned short* __restrict__ FB,
    const unsigned short* __restrict__ UFLR, const unsigned short* __restrict__ UCAT2,
    const unsigned short* __restrict__ WF, const float* __restrict__ biou,
    const float* __restrict__ c_out, float* __restrict__ h_out,
    unsigned short* __restrict__ IOU,
    int P, int shift, int start_l, int start_lm1, int nwg1, int nwg2) {
  __shared__ __align__(16) unsigned short As[128 * 64];
  __shared__ __align__(16) unsigned short Bs[128 * 64];
  const int tid = threadIdx.x;
  const int wid = tid >> 6, lane = tid & 63;
  const int wr = wid >> 1, wc = wid & 1;
  const int lr = lane & 15, lg = lane >> 4;
  const int pmask = (1 << shift) - 1;
  f4v acc[4][4];
#pragma unroll
  for (int i = 0; i < 4; ++i)
#pragma unroll
    for (int j = 0; j < 4; ++j) acc[i][j] = fz4();

  if ((int)blockIdx.x < nwg1) {
    // ===== G1: [2P,512] @ UFLR^T ; fused fc -> h_out =====
    const int swz = xcd_swz(blockIdx.x, nwg1);
    const int tn = swz & 7, tm = swz >> 3;
    const int M2 = 2 * P;
    const int cmask = (2 << shift) - 1;
    const unsigned short* aA[4]; const unsigned short* aB[4];
#pragma unroll
    for (int L = 0; L < 4; ++L) {
      int q = L * 256 + tid;
      int row = q >> 3, c16g = (q & 7) ^ (row & 7);
      int jg = tm * 128 + row; if (jg >= M2) jg = M2 - 1;
      int t = jg >> (shift + 1), idx = jg & cmask;
      aA[L] = HB + (size_t)(t * PER_ + start_lm1 + idx) * 512 + c16g * 8;
      int n = tn * 128 + row;
      aB[L] = UFLR + (size_t)n * 512 + c16g * 8;
    }
    for (int k0 = 0; k0 < 512; k0 += 64) {
#pragma unroll
      for (int L = 0; L < 4; ++L) {
        int q = L * 256 + tid;
        gld16(aA[L] + k0, (unsigned short*)As + q * 8);
        gld16(aB[L] + k0, (unsigned short*)Bs + q * 8);
      }
      __syncthreads();
      MFMA_STEP(As, Bs)
      __syncthreads();
    }
    const int soff = start_l - 1024;           // internal-linear level offset
#pragma unroll
    for (int i = 0; i < 4; ++i) {
      int mbase = tm * 128 + wr * 64 + i * 16;  // even
#pragma unroll
      for (int j = 0; j < 4; ++j) {
        int nn = tn * 128 + wc * 64 + j * 16 + lr;
        int hcol = nn >> 1;
        float fc[4];
#pragma unroll
        for (int r = 0; r < 4; ++r) {
          int m = mbase + lg * 4 + r;           // child row
          int mm = (m < M2) ? m : 0;
          int pidx = mm >> 1;
          int t = pidx >> shift, k = pidx & pmask;
          float wf = bf2f(WF[(size_t)(t * 1023 + soff + k) * 512 + hcol]);
          float sv = sigm(wf + acc[i][j][r]);
          float spair = sv + __shfl_xor(sv, 1, 64);
          float cc = 0.f;
          if ((lr & 1) == 0)
            cc = c_out[(size_t)(t * PER_ + start_lm1 + (mm & cmask)) * 512 + hcol];
          fc[r] = spair * cc;
        }
        if ((lr & 1) == 0) {
          int p0 = (mbase >> 1) + lg * 2;
          if (p0 < P) {
            int t0 = p0 >> shift, k0p = p0 & pmask;
            h_out[(size_t)(t0 * PER_ + start_l + k0p) * 512 + hcol] = fc[0] + fc[1];
          }
          int p1 = (mbase >> 1) + lg * 2 + 1;
          if (p1 < P) {
            int t1 = p1 >> shift, k1p = p1 & pmask;
            h_out[(size_t)(t1 * PER_ + start_l + k1p) * 512 + hcol] = fc[2] + fc[3];
          }
        }
      }
    }
  } else {
    // ===== G2: [P, 1536=(hl|hr|x_p)] @ UCAT2^T + b -> IOU =====
    const int swz = xcd_swz((int)blockIdx.x - nwg1, nwg2);
    const int tn = swz % 12, tm = swz / 12;
    const unsigned short* aHB[4]; const unsigned short* aFB[4];
    const unsigned short* aB[4];
#pragma unroll
    for (int L = 0; L < 4; ++L) {
      int q = L * 256 + tid;
      int row = q >> 3, c16g = (q & 7) ^ (row & 7);
      int p = tm * 128 + row; if (p >= P) p = P - 1;
      int t = p >> shift, kp = p & pmask;
      aHB[L] = HB + (size_t)(t * PER_ + start_lm1) * 512 + (size_t)kp * 1024 + c16g * 8;
      aFB[L] = FB + (size_t)(t * PER_ + start_l + kp) * 512 + c16g * 8;
      int n = tn * 128 + row;
      aB[L] = UCAT2 + (size_t)n * 1536 + c16g * 8;
    }
    for (int k0 = 0; k0 < 1536; k0 += 64) {
#pragma unroll
      for (int L = 0; L < 4; ++L) {
        int q = L * 256 + tid;
        const unsigned short* src = (k0 < 1024) ? aHB[L] + k0 : aFB[L] + (k0 - 1024);
        gld16(src, (unsigned short*)As + q * 8);
        gld16(aB[L] + k0, (unsigned short*)Bs + q * 8);
      }
      __syncthreads();
      MFMA_STEP(As, Bs)
      __syncthreads();
    }
#pragma unroll
    for (int i = 0; i < 4; ++i)
#pragma unroll
      for (int j = 0; j < 4; ++j) {
        int n = tn * 128 + wc * 64 + j * 16 + lr;
        float bias = biou[n];
#pragma unroll
        for (int r = 0; r < 4; ++r) {
          int m = tm * 128 + wr * 64 + i * 16 + lg * 4 + r;
          if (m < P) IOU[(size_t)m * 1536 + n] = f2bf(acc[i][j][r] + bias);
        }
      }
  }
}

// ---- G3: combine; reads fcsum from h_out, overwrites with h -------------
__global__ __launch_bounds__(256) void g3_kernel(
    const unsigned short* __restrict__ IOU,
    float* __restrict__ h_out, float* __restrict__ c_out,
    unsigned short* __restrict__ HB, int P, int shift, int start_l) {
  int idx = blockIdx.x * 256 + threadIdx.x;
  int p = idx >> 7;
  if (p >= P) return;
  int c4 = (idx & 127) << 2;
  int t = p >> shift, k = p & ((1 << shift) - 1);
  size_t pg = (size_t)(t * PER_ + start_l + k);
  const unsigned short* ir = IOU + (size_t)p * 1536;
  ushort4 iv = *(const ushort4*)(ir + c4);
  ushort4 ov = *(const ushort4*)(ir + 512 + c4);
  ushort4 uv = *(const ushort4*)(ir + 1024 + c4);
  float4 fcs = *(const float4*)(h_out + pg * 512 + c4);
  float4 hv, cv; ushort4 hb;
  float cc, hh;
  cc = sigm(bf2f(iv.x)) * tanh_s(bf2f(uv.x)) + fcs.x; hh = sigm(bf2f(ov.x)) * tanh_s(cc);
  cv.x = cc; hv.x = hh; hb.x = f2bf(hh);
  cc = sigm(bf2f(iv.y)) * tanh_s(bf2f(uv.y)) + fcs.y; hh = sigm(bf2f(ov.y)) * tanh_s(cc);
  cv.y = cc; hv.y = hh; hb.y = f2bf(hh);
  cc = sigm(bf2f(iv.z)) * tanh_s(bf2f(uv.z)) + fcs.z; hh = sigm(bf2f(ov.z)) * tanh_s(cc);
  cv.z = cc; hv.z = hh; hb.z = f2bf(hh);
  cc = sigm(bf2f(iv.w)) * tanh_s(bf2f(uv.w)) + fcs.w; hh = sigm(bf2f(ov.w)) * tanh_s(cc);
  cv.w = cc; hv.w = hh; hb.w = f2bf(hh);
  *(float4*)(h_out + pg * 512 + c4) = hv;
  *(float4*)(c_out + pg * 512 + c4) = cv;
  *(ushort4*)(HB + pg * 512 + c4) = hb;
}

__global__ void fill_sentinel(float* out, int n) {
  int i = blockIdx.x * 256 + threadIdx.x;
  if (i < n) out[i] = 12345.0f;
}

// ---------------- host launch -------------------------------------------
extern "C" void kernel_launch(void* const* d_in, const int* in_sizes, int n_in,
                              void* d_out, int out_size, void* d_ws, size_t ws_size,
                              hipStream_t stream) {
  (void)in_sizes; (void)n_in; (void)out_size;
  const float* feat = (const float*)d_in[0];
  const float* Wiou = (const float*)d_in[4];
  const float* biou = (const float*)d_in[5];
  const float* Ul   = (const float*)d_in[6];
  const float* Ur   = (const float*)d_in[7];
  const float* Wf   = (const float*)d_in[8];
  const float* bfb  = (const float*)d_in[9];
  const float* Ufl  = (const float*)d_in[10];
  const float* Ufr  = (const float*)d_in[11];
  float* h_out = (float*)d_out;
  float* c_out = h_out + (size_t)NN_ * 512;

  const size_t OFF_HB   = 0;
  const size_t SZ_HB    = (size_t)NN_ * 512 * 2;          // 104.8 MB
  const size_t OFF_FB   = OFF_HB + SZ_HB;
  const size_t SZ_FB    = (size_t)NN_ * 512 * 2;          // 104.8 MB
  const size_t OFF_WFm  = OFF_FB + SZ_FB;
  const size_t SZ_WF    = (size_t)NINT_ * 512 * 2;        // 52.4 MB
  const size_t OFF_UC2  = OFF_WFm + SZ_WF;
  const size_t SZ_UC2   = 1536 * 1536 * 2;
  const size_t OFF_UFLR = OFF_UC2 + SZ_UC2;
  const size_t SZ_UFLR  = 1024 * 512 * 2;
  const size_t OFF_WFB  = OFF_UFLR + SZ_UFLR;
  const size_t SZ_WFB   = 512 * 512 * 2;
  const size_t OFF_LIOU = OFF_WFB + SZ_WFB;               // LIOU / IOU alias
  const size_t SZ_LIOU  = (size_t)NLEAF_ * 1536 * 2;      // 157.3 MB
  const size_t NEEDED   = OFF_LIOU + SZ_LIOU;

  if (ws_size < NEEDED) {
    int n = 2 * NN_ * 512;
    fill_sentinel<<<(n + 255) / 256, 256, 0, stream>>>((float*)d_out, n);
    return;
  }

  char* ws = (char*)d_ws;
  unsigned short* HB    = (unsigned short*)(ws + OFF_HB);
  unsigned short* FB    = (unsigned short*)(ws + OFF_FB);
  unsigned short* WF    = (unsigned short*)(ws + OFF_WFm);
  unsigned short* UCAT2 = (unsigned short*)(ws + OFF_UC2);
  unsigned short* UFLR  = (unsigned short*)(ws + OFF_UFLR);
  unsigned short* WFB   = (unsigned short*)(ws + OFF_WFB);
  unsigned short* LIOU  = (unsigned short*)(ws + OFF_LIOU);
  unsigned short* IOU   = (unsigned short*)(ws + OFF_LIOU);

  prep_weights<<<9216, 256, 0, stream>>>(Wiou, Ul, Ur, Wf, Ufl, Ufr,
                                         UCAT2, UFLR, WFB);
  feat2bf<<<(NN_ * 64 + 255) / 256, 256, 0, stream>>>(feat, FB);
  {
    int nwg = ((NINT_ + 127) / 128) * 4;       // 400*4
    wf_gemm<<<nwg, 256, 0, stream>>>(FB, WFB, bfb, WF, nwg);
  }
  {
    int nwg = (NLEAF_ / 128) * 12;             // 400*12
    leaf_gemm<<<nwg, 256, 0, stream>>>(FB, UCAT2, biou, LIOU, nwg);
  }
  leaf_ew<<<(NLEAF_ * 128) / 256, 256, 0, stream>>>(LIOU, h_out, c_out, HB);

  for (int l = 1; l <= 10; ++l) {
    int shift = 10 - l;
    int P = TREES_ << shift;
    int start_l   = 2048 - (1 << (11 - l));
    int start_lm1 = 2048 - (1 << (12 - l));
    int nwg1 = ((2 * P + 127) / 128) * 8;
    int nwg2 = ((P + 127) / 128) * 12;
    lvl_gemm<<<nwg1 + nwg2, 256, 0, stream>>>(HB, FB, UFLR, UCAT2, WF, biou,
                                              c_out, h_out, IOU,
                                              P, shift, start_l, start_lm1,
                                              nwg1, nwg2);
    int g3b = (P * 128 + 255) / 256;
    g3_kernel<<<g3b, 256, 0, stream>>>(IOU, h_out, c_out, HB, P, shift, start_l);
  }
}

// Round 6
// 1492.701 us; speedup vs baseline: 2.3622x; 1.0041x over previous
//
#include <hip/hip_runtime.h>
#include <hip/hip_bf16.h>

#define TREES_ 50
#define PER_ 2047
#define NN_ (TREES_ * PER_)      // 102350 nodes
#define NINT_ (TREES_ * 1023)    // 51150 internal nodes
#define NLEAF_ (TREES_ * 1024)   // 51200 leaves

typedef __attribute__((ext_vector_type(8))) short s8v;   // 8 bf16
typedef __attribute__((ext_vector_type(4))) float f4v;   // MFMA C/D

__device__ __forceinline__ unsigned short f2bf(float f) {
  union { float f; unsigned u; } v; v.f = f;
  unsigned r = v.u + 0x7FFFu + ((v.u >> 16) & 1u);   // RNE
  return (unsigned short)(r >> 16);
}
__device__ __forceinline__ float bf2f(unsigned short s) {
  union { unsigned u; float f; } v; v.u = ((unsigned)s) << 16;
  return v.f;
}
__device__ __forceinline__ float sigm(float x) { return 1.f / (1.f + __expf(-x)); }
__device__ __forceinline__ float tanh_s(float x) {
  float ax = fabsf(x);
  float e = __expf(2.f * ax);
  float t = 1.f - 2.f / (e + 1.f);
  return copysignf(t, x);
}
__device__ __forceinline__ f4v fz4() { f4v z; z[0]=0.f; z[1]=0.f; z[2]=0.f; z[3]=0.f; return z; }

#if defined(__has_builtin)
#if __has_builtin(__builtin_amdgcn_global_load_lds)
#define HAS_GLD 1
#endif
#endif
__device__ __forceinline__ void gld16(const void* g, void* l) {
#ifdef HAS_GLD
  __builtin_amdgcn_global_load_lds(
      (const __attribute__((address_space(1))) unsigned int*)g,
      (__attribute__((address_space(3))) unsigned int*)l, 16, 0, 0);
#else
  *(s8v*)l = *(const s8v*)g;
#endif
}

// bijective XCD-chunked swizzle (m204)
__device__ __forceinline__ int xcd_swz(int bid, int nwg) {
  int q = nwg >> 3, r = nwg & 7, x = bid & 7, pos = bid >> 3;
  int base = (x < r) ? x * (q + 1) : r * (q + 1) + (x - r) * q;
  return base + pos;
}

// LDS tile [128 rows][64 bf16]; logical chunk (row,c16) at swizzled byte.
// Staging writes LINEAR slot q=(row,c16s) from global chunk c16g=c16s^(row&7).
#define LDS_BYTE(row, c16) ((row) * 128 + (((c16) ^ ((row) & 7)) << 4))

// one K-step (64) of 128x128 tile, 4 waves; Ap/Bp = LDS half-buffer bases
#define MFMA_STEP(Ap, Bp)                                                     \
  _Pragma("unroll") for (int kk = 0; kk < 2; ++kk) {                          \
    s8v af[4], bf_[4];                                                        \
    _Pragma("unroll") for (int i = 0; i < 4; ++i) {                           \
      int R = wr * 64 + i * 16 + lr;                                          \
      af[i] = *(const s8v*)((const char*)(Ap) + LDS_BYTE(R, kk * 4 + lg));    \
    }                                                                         \
    _Pragma("unroll") for (int j = 0; j < 4; ++j) {                           \
      int R = wc * 64 + j * 16 + lr;                                          \
      bf_[j] = *(const s8v*)((const char*)(Bp) + LDS_BYTE(R, kk * 4 + lg));   \
    }                                                                         \
    _Pragma("unroll") for (int i = 0; i < 4; ++i)                             \
      _Pragma("unroll") for (int j = 0; j < 4; ++j)                           \
        acc[i][j] = __builtin_amdgcn_mfma_f32_16x16x32_bf16(af[i], bf_[j],    \
                                                            acc[i][j], 0, 0, 0); \
  }

#define DRAIN_BARRIER()                                   \
  asm volatile("s_waitcnt vmcnt(0)" ::: "memory");        \
  __syncthreads();

// ---------------- feat fp32 -> bf16 --------------------------------------
__global__ __launch_bounds__(256) void feat2bf(const float* __restrict__ feat,
                                               unsigned short* __restrict__ FB) {
  long long i = (long long)blockIdx.x * 256 + threadIdx.x;
  if (i >= (long long)NN_ * 64) return;
  const float* src = feat + i * 8;
  float4 f0 = *(const float4*)src;
  float4 f1 = *(const float4*)(src + 4);
  s8v v;
  v[0] = (short)f2bf(f0.x); v[1] = (short)f2bf(f0.y);
  v[2] = (short)f2bf(f0.z); v[3] = (short)f2bf(f0.w);
  v[4] = (short)f2bf(f1.x); v[5] = (short)f2bf(f1.y);
  v[6] = (short)f2bf(f1.z); v[7] = (short)f2bf(f1.w);
  *(s8v*)(FB + i * 8) = v;
}

// -------- weight prep --------
// UCAT2 [1536][1536]: row n = [U_iou_l[n] | U_iou_r[n] | W_iou[n]]
// UFLR  [1024][512]:  row 2c=Ufl[c], 2c+1=Ufr[c]
// WFB   [512][512]:   W_f
__global__ __launch_bounds__(256) void prep_weights(
    const float* __restrict__ Wiou, const float* __restrict__ Ul,
    const float* __restrict__ Ur,  const float* __restrict__ Wf,
    const float* __restrict__ Ufl, const float* __restrict__ Ufr,
    unsigned short* __restrict__ UCAT2, unsigned short* __restrict__ UFLR,
    unsigned short* __restrict__ WFB) {
  int i = blockIdx.x * 256 + threadIdx.x;
  if (i < 1536 * 1536) {
    int r = i / 1536, c = i - r * 1536;
    float v = (c < 512) ? Ul[r * 512 + c]
            : (c < 1024) ? Ur[r * 512 + (c - 512)]
                         : Wiou[r * 512 + (c - 1024)];
    UCAT2[i] = f2bf(v);
  }
  if (i < 1024 * 512) {
    int r = i >> 9, k = i & 511;
    int c = r >> 1, s = r & 1;
    UFLR[i] = f2bf(s ? Ufr[c * 512 + k] : Ufl[c * 512 + k]);
  }
  if (i < 512 * 512) WFB[i] = f2bf(Wf[i]);
}

// ---- merged pre GEMMs: bid<nwgW -> WF; else LIOU (leaves) ---------------
__global__ __launch_bounds__(256) void pre_mm(
    const unsigned short* __restrict__ FB, const unsigned short* __restrict__ WFB,
    const unsigned short* __restrict__ UCAT2,
    const float* __restrict__ bfb, const float* __restrict__ biou,
    unsigned short* __restrict__ WF, unsigned short* __restrict__ LIOU,
    int nwgW, int nwgL) {
  __shared__ __align__(16) unsigned short AsB[2 * 128 * 64];
  __shared__ __align__(16) unsigned short BsB[2 * 128 * 64];
  const int tid = threadIdx.x;
  const int wid = tid >> 6, lane = tid & 63;
  const int wr = wid >> 1, wc = wid & 1;
  const int lr = lane & 15, lg = lane >> 4;
  f4v acc[4][4];
#pragma unroll
  for (int i = 0; i < 4; ++i)
#pragma unroll
    for (int j = 0; j < 4; ++j) acc[i][j] = fz4();

  const unsigned short* aA[4]; const unsigned short* aB[4];
  int tm, tn;
  const bool isW = (int)blockIdx.x < nwgW;
  if (isW) {
    const int swz = xcd_swz(blockIdx.x, nwgW);
    tn = swz & 3; tm = swz >> 2;
#pragma unroll
    for (int L = 0; L < 4; ++L) {
      int q = L * 256 + tid;
      int row = q >> 3, c16g = (q & 7) ^ (row & 7);
      int m = tm * 128 + row; if (m >= NINT_) m = NINT_ - 1;
      unsigned t = (unsigned)m / 1023u;
      int node = (int)t * 2047 + 1024 + (m - (int)t * 1023);
      aA[L] = FB + (size_t)node * 512 + c16g * 8;
      int n = tn * 128 + row;
      aB[L] = WFB + (size_t)n * 512 + c16g * 8;
    }
  } else {
    const int swz = xcd_swz((int)blockIdx.x - nwgW, nwgL);
    tn = swz % 12; tm = swz / 12;
#pragma unroll
    for (int L = 0; L < 4; ++L) {
      int q = L * 256 + tid;
      int row = q >> 3, c16g = (q & 7) ^ (row & 7);
      int m = tm * 128 + row;
      int node = (m >> 10) * 2047 + (m & 1023);
      aA[L] = FB + (size_t)node * 512 + c16g * 8;
      int n = tn * 128 + row;
      aB[L] = UCAT2 + (size_t)n * 1536 + 1024 + c16g * 8;  // W_iou slice
    }
  }
#define STAGE_P(bb, kofs)                                         \
  _Pragma("unroll") for (int L = 0; L < 4; ++L) {                 \
    int q = L * 256 + tid;                                        \
    gld16(aA[L] + (kofs), AsB + (bb) * 8192 + q * 8);             \
    gld16(aB[L] + (kofs), BsB + (bb) * 8192 + q * 8);             \
  }
  STAGE_P(0, 0)
  DRAIN_BARRIER()
  int cur = 0;
  for (int t = 0; t < 7; ++t) {
    STAGE_P(cur ^ 1, (t + 1) * 64)
    MFMA_STEP(AsB + cur * 8192, BsB + cur * 8192)
    DRAIN_BARRIER()
    cur ^= 1;
  }
  MFMA_STEP(AsB + cur * 8192, BsB + cur * 8192)

  if (isW) {
#pragma unroll
    for (int i = 0; i < 4; ++i)
#pragma unroll
      for (int j = 0; j < 4; ++j) {
        int n = tn * 128 + wc * 64 + j * 16 + lr;
        float bias = bfb[n];
#pragma unroll
        for (int r = 0; r < 4; ++r) {
          int m = tm * 128 + wr * 64 + i * 16 + lg * 4 + r;
          if (m < NINT_) WF[(size_t)m * 512 + n] = f2bf(acc[i][j][r] + bias);
        }
      }
  } else {
#pragma unroll
    for (int i = 0; i < 4; ++i)
#pragma unroll
      for (int j = 0; j < 4; ++j) {
        int n = tn * 128 + wc * 64 + j * 16 + lr;
        float bias = biou[n];
#pragma unroll
        for (int r = 0; r < 4; ++r) {
          int m = tm * 128 + wr * 64 + i * 16 + lg * 4 + r;
          LIOU[(size_t)m * 1536 + n] = f2bf(acc[i][j][r] + bias);
        }
      }
  }
}

// ---- leaf elementwise ---------------------------------------------------
__global__ __launch_bounds__(256) void leaf_ew(
    const unsigned short* __restrict__ LIOU,
    float* __restrict__ h_out, float* __restrict__ c_out,
    unsigned short* __restrict__ HB) {
  int idx = blockIdx.x * 256 + threadIdx.x;
  int r = idx >> 7;
  int c4 = (idx & 127) << 2;
  int g = (r >> 10) * 2047 + (r & 1023);
  const unsigned short* pr = LIOU + (size_t)r * 1536;
  ushort4 iv = *(const ushort4*)(pr + c4);
  ushort4 ov = *(const ushort4*)(pr + 512 + c4);
  ushort4 uv = *(const ushort4*)(pr + 1024 + c4);
  float4 hv, cv; ushort4 hb;
  float cc, hh;
  cc = sigm(bf2f(iv.x)) * tanh_s(bf2f(uv.x)); hh = sigm(bf2f(ov.x)) * tanh_s(cc);
  cv.x = cc; hv.x = hh; hb.x = f2bf(hh);
  cc = sigm(bf2f(iv.y)) * tanh_s(bf2f(uv.y)); hh = sigm(bf2f(ov.y)) * tanh_s(cc);
  cv.y = cc; hv.y = hh; hb.y = f2bf(hh);
  cc = sigm(bf2f(iv.z)) * tanh_s(bf2f(uv.z)); hh = sigm(bf2f(ov.z)) * tanh_s(cc);
  cv.z = cc; hv.z = hh; hb.z = f2bf(hh);
  cc = sigm(bf2f(iv.w)) * tanh_s(bf2f(uv.w)); hh = sigm(bf2f(ov.w)) * tanh_s(cc);
  cv.w = cc; hv.w = hh; hb.w = f2bf(hh);
  *(float4*)(h_out + (size_t)g * 512 + c4) = hv;
  *(float4*)(c_out + (size_t)g * 512 + c4) = cv;
  *(ushort4*)(HB + (size_t)g * 512 + c4) = hb;
}

// ---- merged level GEMM: bid<nwg1 -> f-gate (G1); else iou (G2) ----------
__global__ __launch_bounds__(256) void lvl_gemm(
    const unsigned short* __restrict__ HB, const unsigned short* __restrict__ FB,
    const unsigned short* __restrict__ UFLR, const unsigned short* __restrict__ UCAT2,
    const unsigned short* __restrict__ WF, const float* __restrict__ biou,
    const float* __restrict__ c_out, float* __restrict__ h_out,
    unsigned short* __restrict__ IOU,
    int P, int shift, int start_l, int start_lm1, int nwg1, int nwg2) {
  __shared__ __align__(16) unsigned short AsB[2 * 128 * 64];
  __shared__ __align__(16) unsigned short BsB[2 * 128 * 64];
  const int tid = threadIdx.x;
  const int wid = tid >> 6, lane = tid & 63;
  const int wr = wid >> 1, wc = wid & 1;
  const int lr = lane & 15, lg = lane >> 4;
  const int pmask = (1 << shift) - 1;
  f4v acc[4][4];
#pragma unroll
  for (int i = 0; i < 4; ++i)
#pragma unroll
    for (int j = 0; j < 4; ++j) acc[i][j] = fz4();

  if ((int)blockIdx.x < nwg1) {
    // ===== G1: [2P,512] @ UFLR^T ; fused fc -> h_out =====
    const int swz = xcd_swz(blockIdx.x, nwg1);
    const int tn = swz & 7, tm = swz >> 3;
    const int M2 = 2 * P;
    const int cmask = (2 << shift) - 1;
    const unsigned short* aA[4]; const unsigned short* aB[4];
#pragma unroll
    for (int L = 0; L < 4; ++L) {
      int q = L * 256 + tid;
      int row = q >> 3, c16g = (q & 7) ^ (row & 7);
      int jg = tm * 128 + row; if (jg >= M2) jg = M2 - 1;
      int t = jg >> (shift + 1), idx = jg & cmask;
      aA[L] = HB + (size_t)(t * PER_ + start_lm1 + idx) * 512 + c16g * 8;
      int n = tn * 128 + row;
      aB[L] = UFLR + (size_t)n * 512 + c16g * 8;
    }
#define STAGE_G1(bb, kofs)                                        \
  _Pragma("unroll") for (int L = 0; L < 4; ++L) {                 \
    int q = L * 256 + tid;                                        \
    gld16(aA[L] + (kofs), AsB + (bb) * 8192 + q * 8);             \
    gld16(aB[L] + (kofs), BsB + (bb) * 8192 + q * 8);             \
  }
    STAGE_G1(0, 0)
    DRAIN_BARRIER()
    int cur = 0;
    for (int t = 0; t < 7; ++t) {
      STAGE_G1(cur ^ 1, (t + 1) * 64)
      MFMA_STEP(AsB + cur * 8192, BsB + cur * 8192)
      DRAIN_BARRIER()
      cur ^= 1;
    }
    MFMA_STEP(AsB + cur * 8192, BsB + cur * 8192)

    const int soff = start_l - 1024;           // internal-linear level offset
#pragma unroll
    for (int i = 0; i < 4; ++i) {
      int mbase = tm * 128 + wr * 64 + i * 16;  // even
#pragma unroll
      for (int j = 0; j < 4; ++j) {
        int nn = tn * 128 + wc * 64 + j * 16 + lr;
        int hcol = nn >> 1;
        float fc[4];
#pragma unroll
        for (int r = 0; r < 4; ++r) {
          int m = mbase + lg * 4 + r;           // child row
          int mm = (m < M2) ? m : 0;
          int pidx = mm >> 1;
          int t = pidx >> shift, k = pidx & pmask;
          float wf = bf2f(WF[(size_t)(t * 1023 + soff + k) * 512 + hcol]);
          float sv = sigm(wf + acc[i][j][r]);
          float spair = sv + __shfl_xor(sv, 1, 64);
          float cc = 0.f;
          if ((lr & 1) == 0)
            cc = c_out[(size_t)(t * PER_ + start_lm1 + (mm & cmask)) * 512 + hcol];
          fc[r] = spair * cc;
        }
        if ((lr & 1) == 0) {
          int p0 = (mbase >> 1) + lg * 2;
          if (p0 < P) {
            int t0 = p0 >> shift, k0p = p0 & pmask;
            h_out[(size_t)(t0 * PER_ + start_l + k0p) * 512 + hcol] = fc[0] + fc[1];
          }
          int p1 = (mbase >> 1) + lg * 2 + 1;
          if (p1 < P) {
            int t1 = p1 >> shift, k1p = p1 & pmask;
            h_out[(size_t)(t1 * PER_ + start_l + k1p) * 512 + hcol] = fc[2] + fc[3];
          }
        }
      }
    }
  } else {
    // ===== G2: [P, 1536=(hl|hr|x_p)] @ UCAT2^T + b -> IOU =====
    const int swz = xcd_swz((int)blockIdx.x - nwg1, nwg2);
    const int tn = swz % 12, tm = swz / 12;
    const unsigned short* aHB[4]; const unsigned short* aFB[4];
    const unsigned short* aB[4];
#pragma unroll
    for (int L = 0; L < 4; ++L) {
      int q = L * 256 + tid;
      int row = q >> 3, c16g = (q & 7) ^ (row & 7);
      int p = tm * 128 + row; if (p >= P) p = P - 1;
      int t = p >> shift, kp = p & pmask;
      aHB[L] = HB + (size_t)(t * PER_ + start_lm1) * 512 + (size_t)kp * 1024 + c16g * 8;
      aFB[L] = FB + (size_t)(t * PER_ + start_l + kp) * 512 + c16g * 8 - 1024;
      int n = tn * 128 + row;
      aB[L] = UCAT2 + (size_t)n * 1536 + c16g * 8;
    }
#define STAGE_G2(bb, kofs)                                                    \
  _Pragma("unroll") for (int L = 0; L < 4; ++L) {                             \
    int q = L * 256 + tid;                                                    \
    const unsigned short* srcA =                                              \
        ((kofs) < 1024) ? aHB[L] + (kofs) : aFB[L] + (kofs);                  \
    gld16(srcA, AsB + (bb) * 8192 + q * 8);                                   \
    gld16(aB[L] + (kofs), BsB + (bb) * 8192 + q * 8);                         \
  }
    STAGE_G2(0, 0)
    DRAIN_BARRIER()
    int cur = 0;
    for (int t = 0; t < 23; ++t) {
      STAGE_G2(cur ^ 1, (t + 1) * 64)
      MFMA_STEP(AsB + cur * 8192, BsB + cur * 8192)
      DRAIN_BARRIER()
      cur ^= 1;
    }
    MFMA_STEP(AsB + cur * 8192, BsB + cur * 8192)
#pragma unroll
    for (int i = 0; i < 4; ++i)
#pragma unroll
      for (int j = 0; j < 4; ++j) {
        int n = tn * 128 + wc * 64 + j * 16 + lr;
        float bias = biou[n];
#pragma unroll
        for (int r = 0; r < 4; ++r) {
          int m = tm * 128 + wr * 64 + i * 16 + lg * 4 + r;
          if (m < P) IOU[(size_t)m * 1536 + n] = f2bf(acc[i][j][r] + bias);
        }
      }
  }
}

// ---- G3: combine; reads fcsum from h_out, overwrites with h -------------
__global__ __launch_bounds__(256) void g3_kernel(
    const unsigned short* __restrict__ IOU,
    float* __restrict__ h_out, float* __restrict__ c_out,
    unsigned short* __restrict__ HB, int P, int shift, int start_l) {
  int idx = blockIdx.x * 256 + threadIdx.x;
  int p = idx >> 7;
  if (p >= P) return;
  int c4 = (idx & 127) << 2;
  int t = p >> shift, k = p & ((1 << shift) - 1);
  size_t pg = (size_t)(t * PER_ + start_l + k);
  const unsigned short* ir = IOU + (size_t)p * 1536;
  ushort4 iv = *(const ushort4*)(ir + c4);
  ushort4 ov = *(const ushort4*)(ir + 512 + c4);
  ushort4 uv = *(const ushort4*)(ir + 1024 + c4);
  float4 fcs = *(const float4*)(h_out + pg * 512 + c4);
  float4 hv, cv; ushort4 hb;
  float cc, hh;
  cc = sigm(bf2f(iv.x)) * tanh_s(bf2f(uv.x)) + fcs.x; hh = sigm(bf2f(ov.x)) * tanh_s(cc);
  cv.x = cc; hv.x = hh; hb.x = f2bf(hh);
  cc = sigm(bf2f(iv.y)) * tanh_s(bf2f(uv.y)) + fcs.y; hh = sigm(bf2f(ov.y)) * tanh_s(cc);
  cv.y = cc; hv.y = hh; hb.y = f2bf(hh);
  cc = sigm(bf2f(iv.z)) * tanh_s(bf2f(uv.z)) + fcs.z; hh = sigm(bf2f(ov.z)) * tanh_s(cc);
  cv.z = cc; hv.z = hh; hb.z = f2bf(hh);
  cc = sigm(bf2f(iv.w)) * tanh_s(bf2f(uv.w)) + fcs.w; hh = sigm(bf2f(ov.w)) * tanh_s(cc);
  cv.w = cc; hv.w = hh; hb.w = f2bf(hh);
  *(float4*)(h_out + pg * 512 + c4) = hv;
  *(float4*)(c_out + pg * 512 + c4) = cv;
  *(ushort4*)(HB + pg * 512 + c4) = hb;
}

__global__ void fill_sentinel(float* out, int n) {
  int i = blockIdx.x * 256 + threadIdx.x;
  if (i < n) out[i] = 12345.0f;
}

// ---------------- host launch -------------------------------------------
extern "C" void kernel_launch(void* const* d_in, const int* in_sizes, int n_in,
                              void* d_out, int out_size, void* d_ws, size_t ws_size,
                              hipStream_t stream) {
  (void)in_sizes; (void)n_in; (void)out_size;
  const float* feat = (const float*)d_in[0];
  const float* Wiou = (const float*)d_in[4];
  const float* biou = (const float*)d_in[5];
  const float* Ul   = (const float*)d_in[6];
  const float* Ur   = (const float*)d_in[7];
  const float* Wf   = (const float*)d_in[8];
  const float* bfb  = (const float*)d_in[9];
  const float* Ufl  = (const float*)d_in[10];
  const float* Ufr  = (const float*)d_in[11];
  float* h_out = (float*)d_out;
  float* c_out = h_out + (size_t)NN_ * 512;

  const size_t OFF_HB   = 0;
  const size_t SZ_HB    = (size_t)NN_ * 512 * 2;
  const size_t OFF_FB   = OFF_HB + SZ_HB;
  const size_t SZ_FB    = (size_t)NN_ * 512 * 2;
  const size_t OFF_WFm  = OFF_FB + SZ_FB;
  const size_t SZ_WF    = (size_t)NINT_ * 512 * 2;
  const size_t OFF_UC2  = OFF_WFm + SZ_WF;
  const size_t SZ_UC2   = 1536 * 1536 * 2;
  const size_t OFF_UFLR = OFF_UC2 + SZ_UC2;
  const size_t SZ_UFLR  = 1024 * 512 * 2;
  const size_t OFF_WFB  = OFF_UFLR + SZ_UFLR;
  const size_t SZ_WFB   = 512 * 512 * 2;
  const size_t OFF_LIOU = OFF_WFB + SZ_WFB;               // LIOU / IOU alias
  const size_t SZ_LIOU  = (size_t)NLEAF_ * 1536 * 2;
  const size_t NEEDED   = OFF_LIOU + SZ_LIOU;

  if (ws_size < NEEDED) {
    int n = 2 * NN_ * 512;
    fill_sentinel<<<(n + 255) / 256, 256, 0, stream>>>((float*)d_out, n);
    return;
  }

  char* ws = (char*)d_ws;
  unsigned short* HB    = (unsigned short*)(ws + OFF_HB);
  unsigned short* FB    = (unsigned short*)(ws + OFF_FB);
  unsigned short* WF    = (unsigned short*)(ws + OFF_WFm);
  unsigned short* UCAT2 = (unsigned short*)(ws + OFF_UC2);
  unsigned short* UFLR  = (unsigned short*)(ws + OFF_UFLR);
  unsigned short* WFB   = (unsigned short*)(ws + OFF_WFB);
  unsigned short* LIOU  = (unsigned short*)(ws + OFF_LIOU);
  unsigned short* IOU   = (unsigned short*)(ws + OFF_LIOU);

  prep_weights<<<9216, 256, 0, stream>>>(Wiou, Ul, Ur, Wf, Ufl, Ufr,
                                         UCAT2, UFLR, WFB);
  feat2bf<<<(NN_ * 64 + 255) / 256, 256, 0, stream>>>(feat, FB);
  {
    int nwgW = ((NINT_ + 127) / 128) * 4;      // 1600
    int nwgL = (NLEAF_ / 128) * 12;            // 4800
    pre_mm<<<nwgW + nwgL, 256, 0, stream>>>(FB, WFB, UCAT2, bfb, biou,
                                            WF, LIOU, nwgW, nwgL);
  }
  leaf_ew<<<(NLEAF_ * 128) / 256, 256, 0, stream>>>(LIOU, h_out, c_out, HB);

  for (int l = 1; l <= 10; ++l) {
    int shift = 10 - l;
    int P = TREES_ << shift;
    int start_l   = 2048 - (1 << (11 - l));
    int start_lm1 = 2048 - (1 << (12 - l));
    int nwg1 = ((2 * P + 127) / 128) * 8;
    int nwg2 = ((P + 127) / 128) * 12;
    lvl_gemm<<<nwg1 + nwg2, 256, 0, stream>>>(HB, FB, UFLR, UCAT2, WF, biou,
                                              c_out, h_out, IOU,
                                              P, shift, start_l, start_lm1,
                                              nwg1, nwg2);
    int g3b = (P * 128 + 255) / 256;
    g3_kernel<<<g3b, 256, 0, stream>>>(IOU, h_out, c_out, HB, P, shift, start_l);
  }
}

// Round 7
// 1459.685 us; speedup vs baseline: 2.4156x; 1.0226x over previous
//
#include <hip/hip_runtime.h>
#include <hip/hip_bf16.h>

#define TREES_ 50
#define PER_ 2047
#define NN_ (TREES_ * PER_)      // 102350 nodes
#define NINT_ (TREES_ * 1023)    // 51150 internal nodes
#define NLEAF_ (TREES_ * 1024)   // 51200 leaves

typedef __attribute__((ext_vector_type(8))) short s8v;   // 8 bf16
typedef __attribute__((ext_vector_type(4))) float f4v;   // MFMA C/D

__device__ __forceinline__ unsigned short f2bf(float f) {
  union { float f; unsigned u; } v; v.f = f;
  unsigned r = v.u + 0x7FFFu + ((v.u >> 16) & 1u);   // RNE
  return (unsigned short)(r >> 16);
}
__device__ __forceinline__ float bf2f(unsigned short s) {
  union { unsigned u; float f; } v; v.u = ((unsigned)s) << 16;
  return v.f;
}
__device__ __forceinline__ float sigm(float x) { return 1.f / (1.f + __expf(-x)); }
__device__ __forceinline__ float tanh_s(float x) {
  float ax = fabsf(x);
  float e = __expf(2.f * ax);
  float t = 1.f - 2.f / (e + 1.f);
  return copysignf(t, x);
}
__device__ __forceinline__ f4v fz4() { f4v z; z[0]=0.f; z[1]=0.f; z[2]=0.f; z[3]=0.f; return z; }

#if defined(__has_builtin)
#if __has_builtin(__builtin_amdgcn_global_load_lds)
#define HAS_GLD 1
#endif
#endif
__device__ __forceinline__ void gld16(const void* g, void* l) {
#ifdef HAS_GLD
  __builtin_amdgcn_global_load_lds(
      (const __attribute__((address_space(1))) unsigned int*)g,
      (__attribute__((address_space(3))) unsigned int*)l, 16, 0, 0);
#else
  *(s8v*)l = *(const s8v*)g;
#endif
}

// bijective XCD-chunked swizzle (m204)
__device__ __forceinline__ int xcd_swz(int bid, int nwg) {
  int q = nwg >> 3, r = nwg & 7, x = bid & 7, pos = bid >> 3;
  int base = (x < r) ? x * (q + 1) : r * (q + 1) + (x - r) * q;
  return base + pos;
}

// LDS tile [128 rows][64 bf16]; logical chunk (row,c16) at swizzled byte.
// Staging writes LINEAR slot q=(row,c16s) from global chunk c16g=c16s^(row&7).
#define LDS_BYTE(row, c16) ((row) * 128 + (((c16) ^ ((row) & 7)) << 4))

// one K-step (64) of 128x128 tile, 4 waves; Ap/Bp = LDS half-buffer bases
#define MFMA_STEP(Ap, Bp)                                                     \
  _Pragma("unroll") for (int kk = 0; kk < 2; ++kk) {                          \
    s8v af[4], bf_[4];                                                        \
    _Pragma("unroll") for (int i = 0; i < 4; ++i) {                           \
      int R = wr * 64 + i * 16 + lr;                                          \
      af[i] = *(const s8v*)((const char*)(Ap) + LDS_BYTE(R, kk * 4 + lg));    \
    }                                                                         \
    _Pragma("unroll") for (int j = 0; j < 4; ++j) {                           \
      int R = wc * 64 + j * 16 + lr;                                          \
      bf_[j] = *(const s8v*)((const char*)(Bp) + LDS_BYTE(R, kk * 4 + lg));   \
    }                                                                         \
    _Pragma("unroll") for (int i = 0; i < 4; ++i)                             \
      _Pragma("unroll") for (int j = 0; j < 4; ++j)                           \
        acc[i][j] = __builtin_amdgcn_mfma_f32_16x16x32_bf16(af[i], bf_[j],    \
                                                            acc[i][j], 0, 0, 0); \
  }

#define VMCNT8() asm volatile("s_waitcnt vmcnt(8)" ::: "memory")
#define VMCNT0() asm volatile("s_waitcnt vmcnt(0)" ::: "memory")
#define LGKM0()  asm volatile("s_waitcnt lgkmcnt(0)" ::: "memory")
#define SBAR()   __builtin_amdgcn_s_barrier()
#define SCHEDB() __builtin_amdgcn_sched_barrier(0)

// counted-vmcnt 2-deep pipeline (T3/T4): tile t+1's 8 loads stay in flight
// across the barrier; tile t+2 staged into the buffer all waves just finished
// reading (guarded by lgkmcnt(0) + barrier).
#define PIPELINE(STAGEM, NT)                                       \
  STAGEM(0, 0)                                                     \
  STAGEM(1, 64)                                                    \
  {                                                                \
    int cur = 0;                                                   \
    for (int t = 0; t < (NT) - 1; ++t) {                           \
      VMCNT8(); SBAR();                                            \
      __builtin_amdgcn_s_setprio(1);                               \
      MFMA_STEP(AsB + cur * 8192, BsB + cur * 8192)                \
      __builtin_amdgcn_s_setprio(0);                               \
      LGKM0(); SCHEDB(); SBAR();                                   \
      if (t + 2 < (NT)) { STAGEM(cur, (t + 2) * 64) }              \
      cur ^= 1;                                                    \
    }                                                              \
    VMCNT0(); SBAR();                                              \
    MFMA_STEP(AsB + cur * 8192, BsB + cur * 8192)                  \
  }

// ---------------- feat fp32 -> bf16 --------------------------------------
__global__ __launch_bounds__(256) void feat2bf(const float* __restrict__ feat,
                                               unsigned short* __restrict__ FB) {
  long long i = (long long)blockIdx.x * 256 + threadIdx.x;
  if (i >= (long long)NN_ * 64) return;
  const float* src = feat + i * 8;
  float4 f0 = *(const float4*)src;
  float4 f1 = *(const float4*)(src + 4);
  s8v v;
  v[0] = (short)f2bf(f0.x); v[1] = (short)f2bf(f0.y);
  v[2] = (short)f2bf(f0.z); v[3] = (short)f2bf(f0.w);
  v[4] = (short)f2bf(f1.x); v[5] = (short)f2bf(f1.y);
  v[6] = (short)f2bf(f1.z); v[7] = (short)f2bf(f1.w);
  *(s8v*)(FB + i * 8) = v;
}

// -------- weight prep --------
// UCAT2 [1536][1536]: row n = [U_iou_l[n] | U_iou_r[n] | W_iou[n]]
// UFLR  [1024][512]:  row 2c=Ufl[c], 2c+1=Ufr[c]
// WFB   [512][512]:   W_f
__global__ __launch_bounds__(256) void prep_weights(
    const float* __restrict__ Wiou, const float* __restrict__ Ul,
    const float* __restrict__ Ur,  const float* __restrict__ Wf,
    const float* __restrict__ Ufl, const float* __restrict__ Ufr,
    unsigned short* __restrict__ UCAT2, unsigned short* __restrict__ UFLR,
    unsigned short* __restrict__ WFB) {
  int i = blockIdx.x * 256 + threadIdx.x;
  if (i < 1536 * 1536) {
    int r = i / 1536, c = i - r * 1536;
    float v = (c < 512) ? Ul[r * 512 + c]
            : (c < 1024) ? Ur[r * 512 + (c - 512)]
                         : Wiou[r * 512 + (c - 1024)];
    UCAT2[i] = f2bf(v);
  }
  if (i < 1024 * 512) {
    int r = i >> 9, k = i & 511;
    int c = r >> 1, s = r & 1;
    UFLR[i] = f2bf(s ? Ufr[c * 512 + k] : Ufl[c * 512 + k]);
  }
  if (i < 512 * 512) WFB[i] = f2bf(Wf[i]);
}

// ---- merged pre GEMMs: bid<nwgW -> WF; else LIOU (leaves) ---------------
__global__ __launch_bounds__(256) void pre_mm(
    const unsigned short* __restrict__ FB, const unsigned short* __restrict__ WFB,
    const unsigned short* __restrict__ UCAT2,
    const float* __restrict__ bfb, const float* __restrict__ biou,
    unsigned short* __restrict__ WF, unsigned short* __restrict__ LIOU,
    int nwgW, int nwgL) {
  __shared__ __align__(16) unsigned short AsB[2 * 128 * 64];
  __shared__ __align__(16) unsigned short BsB[2 * 128 * 64];
  const int tid = threadIdx.x;
  const int wid = tid >> 6, lane = tid & 63;
  const int wr = wid >> 1, wc = wid & 1;
  const int lr = lane & 15, lg = lane >> 4;
  f4v acc[4][4];
#pragma unroll
  for (int i = 0; i < 4; ++i)
#pragma unroll
    for (int j = 0; j < 4; ++j) acc[i][j] = fz4();

  const unsigned short* aA[4]; const unsigned short* aB[4];
  int tm, tn;
  const bool isW = (int)blockIdx.x < nwgW;
  if (isW) {
    const int swz = xcd_swz(blockIdx.x, nwgW);
    tn = swz & 3; tm = swz >> 2;
#pragma unroll
    for (int L = 0; L < 4; ++L) {
      int q = L * 256 + tid;
      int row = q >> 3, c16g = (q & 7) ^ (row & 7);
      int m = tm * 128 + row; if (m >= NINT_) m = NINT_ - 1;
      unsigned t = (unsigned)m / 1023u;
      int node = (int)t * 2047 + 1024 + (m - (int)t * 1023);
      aA[L] = FB + (size_t)node * 512 + c16g * 8;
      int n = tn * 128 + row;
      aB[L] = WFB + (size_t)n * 512 + c16g * 8;
    }
  } else {
    const int swz = xcd_swz((int)blockIdx.x - nwgW, nwgL);
    tn = swz % 12; tm = swz / 12;
#pragma unroll
    for (int L = 0; L < 4; ++L) {
      int q = L * 256 + tid;
      int row = q >> 3, c16g = (q & 7) ^ (row & 7);
      int m = tm * 128 + row;
      int node = (m >> 10) * 2047 + (m & 1023);
      aA[L] = FB + (size_t)node * 512 + c16g * 8;
      int n = tn * 128 + row;
      aB[L] = UCAT2 + (size_t)n * 1536 + 1024 + c16g * 8;  // W_iou slice
    }
  }
#define STAGE_P(bb, kofs)                                         \
  _Pragma("unroll") for (int L = 0; L < 4; ++L) {                 \
    int q = L * 256 + tid;                                        \
    gld16(aA[L] + (kofs), AsB + (bb) * 8192 + q * 8);             \
    gld16(aB[L] + (kofs), BsB + (bb) * 8192 + q * 8);             \
  }
  PIPELINE(STAGE_P, 8)

  if (isW) {
#pragma unroll
    for (int i = 0; i < 4; ++i)
#pragma unroll
      for (int j = 0; j < 4; ++j) {
        int n = tn * 128 + wc * 64 + j * 16 + lr;
        float bias = bfb[n];
#pragma unroll
        for (int r = 0; r < 4; ++r) {
          int m = tm * 128 + wr * 64 + i * 16 + lg * 4 + r;
          if (m < NINT_) WF[(size_t)m * 512 + n] = f2bf(acc[i][j][r] + bias);
        }
      }
  } else {
#pragma unroll
    for (int i = 0; i < 4; ++i)
#pragma unroll
      for (int j = 0; j < 4; ++j) {
        int n = tn * 128 + wc * 64 + j * 16 + lr;
        float bias = biou[n];
#pragma unroll
        for (int r = 0; r < 4; ++r) {
          int m = tm * 128 + wr * 64 + i * 16 + lg * 4 + r;
          LIOU[(size_t)m * 1536 + n] = f2bf(acc[i][j][r] + bias);
        }
      }
  }
}

// ---- leaf elementwise ---------------------------------------------------
__global__ __launch_bounds__(256) void leaf_ew(
    const unsigned short* __restrict__ LIOU,
    float* __restrict__ h_out, float* __restrict__ c_out,
    unsigned short* __restrict__ HB) {
  int idx = blockIdx.x * 256 + threadIdx.x;
  int r = idx >> 7;
  int c4 = (idx & 127) << 2;
  int g = (r >> 10) * 2047 + (r & 1023);
  const unsigned short* pr = LIOU + (size_t)r * 1536;
  ushort4 iv = *(const ushort4*)(pr + c4);
  ushort4 ov = *(const ushort4*)(pr + 512 + c4);
  ushort4 uv = *(const ushort4*)(pr + 1024 + c4);
  float4 hv, cv; ushort4 hb;
  float cc, hh;
  cc = sigm(bf2f(iv.x)) * tanh_s(bf2f(uv.x)); hh = sigm(bf2f(ov.x)) * tanh_s(cc);
  cv.x = cc; hv.x = hh; hb.x = f2bf(hh);
  cc = sigm(bf2f(iv.y)) * tanh_s(bf2f(uv.y)); hh = sigm(bf2f(ov.y)) * tanh_s(cc);
  cv.y = cc; hv.y = hh; hb.y = f2bf(hh);
  cc = sigm(bf2f(iv.z)) * tanh_s(bf2f(uv.z)); hh = sigm(bf2f(ov.z)) * tanh_s(cc);
  cv.z = cc; hv.z = hh; hb.z = f2bf(hh);
  cc = sigm(bf2f(iv.w)) * tanh_s(bf2f(uv.w)); hh = sigm(bf2f(ov.w)) * tanh_s(cc);
  cv.w = cc; hv.w = hh; hb.w = f2bf(hh);
  *(float4*)(h_out + (size_t)g * 512 + c4) = hv;
  *(float4*)(c_out + (size_t)g * 512 + c4) = cv;
  *(ushort4*)(HB + (size_t)g * 512 + c4) = hb;
}

// ---- merged level GEMM: bid<nwg1 -> f-gate (G1); else iou (G2) ----------
__global__ __launch_bounds__(256) void lvl_gemm(
    const unsigned short* __restrict__ HB, const unsigned short* __restrict__ FB,
    const unsigned short* __restrict__ UFLR, const unsigned short* __restrict__ UCAT2,
    const unsigned short* __restrict__ WF, const float* __restrict__ biou,
    const float* __restrict__ c_out, float* __restrict__ h_out,
    unsigned short* __restrict__ IOU,
    int P, int shift, int start_l, int start_lm1, int nwg1, int nwg2) {
  __shared__ __align__(16) unsigned short AsB[2 * 128 * 64];
  __shared__ __align__(16) unsigned short BsB[2 * 128 * 64];
  const int tid = threadIdx.x;
  const int wid = tid >> 6, lane = tid & 63;
  const int wr = wid >> 1, wc = wid & 1;
  const int lr = lane & 15, lg = lane >> 4;
  const int pmask = (1 << shift) - 1;
  f4v acc[4][4];
#pragma unroll
  for (int i = 0; i < 4; ++i)
#pragma unroll
    for (int j = 0; j < 4; ++j) acc[i][j] = fz4();

  if ((int)blockIdx.x < nwg1) {
    // ===== G1: [2P,512] @ UFLR^T ; fused fc -> h_out =====
    const int swz = xcd_swz(blockIdx.x, nwg1);
    const int tn = swz & 7, tm = swz >> 3;
    const int M2 = 2 * P;
    const int cmask = (2 << shift) - 1;
    const unsigned short* aA[4]; const unsigned short* aB[4];
#pragma unroll
    for (int L = 0; L < 4; ++L) {
      int q = L * 256 + tid;
      int row = q >> 3, c16g = (q & 7) ^ (row & 7);
      int jg = tm * 128 + row; if (jg >= M2) jg = M2 - 1;
      int t = jg >> (shift + 1), idx = jg & cmask;
      aA[L] = HB + (size_t)(t * PER_ + start_lm1 + idx) * 512 + c16g * 8;
      int n = tn * 128 + row;
      aB[L] = UFLR + (size_t)n * 512 + c16g * 8;
    }
#define STAGE_G1(bb, kofs)                                        \
  _Pragma("unroll") for (int L = 0; L < 4; ++L) {                 \
    int q = L * 256 + tid;                                        \
    gld16(aA[L] + (kofs), AsB + (bb) * 8192 + q * 8);             \
    gld16(aB[L] + (kofs), BsB + (bb) * 8192 + q * 8);             \
  }
    PIPELINE(STAGE_G1, 8)

    const int soff = start_l - 1024;           // internal-linear level offset
#pragma unroll
    for (int i = 0; i < 4; ++i) {
      int mbase = tm * 128 + wr * 64 + i * 16;  // even
#pragma unroll
      for (int j = 0; j < 4; ++j) {
        int nn = tn * 128 + wc * 64 + j * 16 + lr;
        int hcol = nn >> 1;
        float fc[4];
#pragma unroll
        for (int r = 0; r < 4; ++r) {
          int m = mbase + lg * 4 + r;           // child row
          int mm = (m < M2) ? m : 0;
          int pidx = mm >> 1;
          int t = pidx >> shift, k = pidx & pmask;
          float wf = bf2f(WF[(size_t)(t * 1023 + soff + k) * 512 + hcol]);
          float sv = sigm(wf + acc[i][j][r]);
          float spair = sv + __shfl_xor(sv, 1, 64);
          float cc = 0.f;
          if ((lr & 1) == 0)
            cc = c_out[(size_t)(t * PER_ + start_lm1 + (mm & cmask)) * 512 + hcol];
          fc[r] = spair * cc;
        }
        if ((lr & 1) == 0) {
          int p0 = (mbase >> 1) + lg * 2;
          if (p0 < P) {
            int t0 = p0 >> shift, k0p = p0 & pmask;
            h_out[(size_t)(t0 * PER_ + start_l + k0p) * 512 + hcol] = fc[0] + fc[1];
          }
          int p1 = (mbase >> 1) + lg * 2 + 1;
          if (p1 < P) {
            int t1 = p1 >> shift, k1p = p1 & pmask;
            h_out[(size_t)(t1 * PER_ + start_l + k1p) * 512 + hcol] = fc[2] + fc[3];
          }
        }
      }
    }
  } else {
    // ===== G2: [P, 1536=(hl|hr|x_p)] @ UCAT2^T + b -> IOU =====
    const int swz = xcd_swz((int)blockIdx.x - nwg1, nwg2);
    const int tn = swz % 12, tm = swz / 12;
    const unsigned short* aHB[4]; const unsigned short* aFB[4];
    const unsigned short* aB[4];
#pragma unroll
    for (int L = 0; L < 4; ++L) {
      int q = L * 256 + tid;
      int row = q >> 3, c16g = (q & 7) ^ (row & 7);
      int p = tm * 128 + row; if (p >= P) p = P - 1;
      int t = p >> shift, kp = p & pmask;
      aHB[L] = HB + (size_t)(t * PER_ + start_lm1) * 512 + (size_t)kp * 1024 + c16g * 8;
      aFB[L] = FB + (size_t)(t * PER_ + start_l + kp) * 512 + c16g * 8 - 1024;
      int n = tn * 128 + row;
      aB[L] = UCAT2 + (size_t)n * 1536 + c16g * 8;
    }
#define STAGE_G2(bb, kofs)                                                    \
  _Pragma("unroll") for (int L = 0; L < 4; ++L) {                             \
    int q = L * 256 + tid;                                                    \
    const unsigned short* srcA =                                              \
        ((kofs) < 1024) ? aHB[L] + (kofs) : aFB[L] + (kofs);                  \
    gld16(srcA, AsB + (bb) * 8192 + q * 8);                                   \
    gld16(aB[L] + (kofs), BsB + (bb) * 8192 + q * 8);                         \
  }
    PIPELINE(STAGE_G2, 24)
#pragma unroll
    for (int i = 0; i < 4; ++i)
#pragma unroll
      for (int j = 0; j < 4; ++j) {
        int n = tn * 128 + wc * 64 + j * 16 + lr;
        float bias = biou[n];
#pragma unroll
        for (int r = 0; r < 4; ++r) {
          int m = tm * 128 + wr * 64 + i * 16 + lg * 4 + r;
          if (m < P) IOU[(size_t)m * 1536 + n] = f2bf(acc[i][j][r] + bias);
        }
      }
  }
}

// ---- G3: combine; reads fcsum from h_out, overwrites with h -------------
__global__ __launch_bounds__(256) void g3_kernel(
    const unsigned short* __restrict__ IOU,
    float* __restrict__ h_out, float* __restrict__ c_out,
    unsigned short* __restrict__ HB, int P, int shift, int start_l) {
  int idx = blockIdx.x * 256 + threadIdx.x;
  int p = idx >> 7;
  if (p >= P) return;
  int c4 = (idx & 127) << 2;
  int t = p >> shift, k = p & ((1 << shift) - 1);
  size_t pg = (size_t)(t * PER_ + start_l + k);
  const unsigned short* ir = IOU + (size_t)p * 1536;
  ushort4 iv = *(const ushort4*)(ir + c4);
  ushort4 ov = *(const ushort4*)(ir + 512 + c4);
  ushort4 uv = *(const ushort4*)(ir + 1024 + c4);
  float4 fcs = *(const float4*)(h_out + pg * 512 + c4);
  float4 hv, cv; ushort4 hb;
  float cc, hh;
  cc = sigm(bf2f(iv.x)) * tanh_s(bf2f(uv.x)) + fcs.x; hh = sigm(bf2f(ov.x)) * tanh_s(cc);
  cv.x = cc; hv.x = hh; hb.x = f2bf(hh);
  cc = sigm(bf2f(iv.y)) * tanh_s(bf2f(uv.y)) + fcs.y; hh = sigm(bf2f(ov.y)) * tanh_s(cc);
  cv.y = cc; hv.y = hh; hb.y = f2bf(hh);
  cc = sigm(bf2f(iv.z)) * tanh_s(bf2f(uv.z)) + fcs.z; hh = sigm(bf2f(ov.z)) * tanh_s(cc);
  cv.z = cc; hv.z = hh; hb.z = f2bf(hh);
  cc = sigm(bf2f(iv.w)) * tanh_s(bf2f(uv.w)) + fcs.w; hh = sigm(bf2f(ov.w)) * tanh_s(cc);
  cv.w = cc; hv.w = hh; hb.w = f2bf(hh);
  *(float4*)(h_out + pg * 512 + c4) = hv;
  *(float4*)(c_out + pg * 512 + c4) = cv;
  *(ushort4*)(HB + pg * 512 + c4) = hb;
}

__global__ void fill_sentinel(float* out, int n) {
  int i = blockIdx.x * 256 + threadIdx.x;
  if (i < n) out[i] = 12345.0f;
}

// ---------------- host launch -------------------------------------------
extern "C" void kernel_launch(void* const* d_in, const int* in_sizes, int n_in,
                              void* d_out, int out_size, void* d_ws, size_t ws_size,
                              hipStream_t stream) {
  (void)in_sizes; (void)n_in; (void)out_size;
  const float* feat = (const float*)d_in[0];
  const float* Wiou = (const float*)d_in[4];
  const float* biou = (const float*)d_in[5];
  const float* Ul   = (const float*)d_in[6];
  const float* Ur   = (const float*)d_in[7];
  const float* Wf   = (const float*)d_in[8];
  const float* bfb  = (const float*)d_in[9];
  const float* Ufl  = (const float*)d_in[10];
  const float* Ufr  = (const float*)d_in[11];
  float* h_out = (float*)d_out;
  float* c_out = h_out + (size_t)NN_ * 512;

  const size_t OFF_HB   = 0;
  const size_t SZ_HB    = (size_t)NN_ * 512 * 2;
  const size_t OFF_FB   = OFF_HB + SZ_HB;
  const size_t SZ_FB    = (size_t)NN_ * 512 * 2;
  const size_t OFF_WFm  = OFF_FB + SZ_FB;
  const size_t SZ_WF    = (size_t)NINT_ * 512 * 2;
  const size_t OFF_UC2  = OFF_WFm + SZ_WF;
  const size_t SZ_UC2   = 1536 * 1536 * 2;
  const size_t OFF_UFLR = OFF_UC2 + SZ_UC2;
  const size_t SZ_UFLR  = 1024 * 512 * 2;
  const size_t OFF_WFB  = OFF_UFLR + SZ_UFLR;
  const size_t SZ_WFB   = 512 * 512 * 2;
  const size_t OFF_LIOU = OFF_WFB + SZ_WFB;               // LIOU / IOU alias
  const size_t SZ_LIOU  = (size_t)NLEAF_ * 1536 * 2;
  const size_t NEEDED   = OFF_LIOU + SZ_LIOU;

  if (ws_size < NEEDED) {
    int n = 2 * NN_ * 512;
    fill_sentinel<<<(n + 255) / 256, 256, 0, stream>>>((float*)d_out, n);
    return;
  }

  char* ws = (char*)d_ws;
  unsigned short* HB    = (unsigned short*)(ws + OFF_HB);
  unsigned short* FB    = (unsigned short*)(ws + OFF_FB);
  unsigned short* WF    = (unsigned short*)(ws + OFF_WFm);
  unsigned short* UCAT2 = (unsigned short*)(ws + OFF_UC2);
  unsigned short* UFLR  = (unsigned short*)(ws + OFF_UFLR);
  unsigned short* WFB   = (unsigned short*)(ws + OFF_WFB);
  unsigned short* LIOU  = (unsigned short*)(ws + OFF_LIOU);
  unsigned short* IOU   = (unsigned short*)(ws + OFF_LIOU);

  prep_weights<<<9216, 256, 0, stream>>>(Wiou, Ul, Ur, Wf, Ufl, Ufr,
                                         UCAT2, UFLR, WFB);
  feat2bf<<<(NN_ * 64 + 255) / 256, 256, 0, stream>>>(feat, FB);
  {
    int nwgW = ((NINT_ + 127) / 128) * 4;      // 1600
    int nwgL = (NLEAF_ / 128) * 12;            // 4800
    pre_mm<<<nwgW + nwgL, 256, 0, stream>>>(FB, WFB, UCAT2, bfb, biou,
                                            WF, LIOU, nwgW, nwgL);
  }
  leaf_ew<<<(NLEAF_ * 128) / 256, 256, 0, stream>>>(LIOU, h_out, c_out, HB);

  for (int l = 1; l <= 10; ++l) {
    int shift = 10 - l;
    int P = TREES_ << shift;
    int start_l   = 2048 - (1 << (11 - l));
    int start_lm1 = 2048 - (1 << (12 - l));
    int nwg1 = ((2 * P + 127) / 128) * 8;
    int nwg2 = ((P + 127) / 128) * 12;
    lvl_gemm<<<nwg1 + nwg2, 256, 0, stream>>>(HB, FB, UFLR, UCAT2, WF, biou,
                                              c_out, h_out, IOU,
                                              P, shift, start_l, start_lm1,
                                              nwg1, nwg2);
    int g3b = (P * 128 + 255) / 256;
    g3_kernel<<<g3b, 256, 0, stream>>>(IOU, h_out, c_out, HB, P, shift, start_l);
  }
}